// Round 3
// baseline (466.451 us; speedup 1.0000x reference)
//
#include <hip/hip_runtime.h>
#include <hip/hip_fp16.h>
#include <cstdint>
#include <cstddef>
#include <type_traits>

#define N_NODES 30000
#define N_EDGES 480000
#define N_EDGES_SL (N_EDGES + N_NODES) // 510000
#define IN_CH 128
#define HEADS1 5
#define C1 64
#define D1 (HEADS1 * C1) // 320
#define OUT_CH 64
#define PE_CNT 100000
#define NEG_SLOPE 0.2f
#define BCAP 64  // bucket capacity; slot 0 = self-loop, ranks 0..62 = edges, rank>=63 -> overflow
#define GEMM1_BLOCKS 469
#define PASS_BLOCKS 32   // R22: node-range-partitioned CSR build. Each block owns
                         // 938 nodes, scans ALL edges (3.84MB, L2-resident), ranks
                         // via block-private LDS counters. ZERO global atomics on
                         // the hot path. R19/R20/R21 proved returning global
                         // atomicAdd is throughput-capped (~8/ns) regardless of
                         // blocks/ILP/padding — so the atomics are eliminated.
#define NODES_PER_PB ((N_NODES + PASS_BLOCKS - 1) / PASS_BLOCKS) // 938

typedef _Float16 f16x8 __attribute__((ext_vector_type(8)));
typedef _Float16 f16x2 __attribute__((ext_vector_type(2)));
typedef float fx4 __attribute__((ext_vector_type(4)));

#if defined(__has_builtin)
#if __has_builtin(__builtin_amdgcn_fdot2)
#define HAS_FDOT2 1
#endif
#endif

static __device__ __forceinline__ float leaky(float x) {
    return fmaxf(x, NEG_SLOPE * x); // valid for 0<slope<1
}

// ---------------- barrier-free MFMA fp16 GEMM phase + fused attention scores ----------------
// Wave-slot per 16-row tile (30000 = 16*1875). No LDS, no barriers.
// mfma_f32_16x16x32_f16 layouts (HW-verified): A: lane holds A[m=lane&15][k=quad*8+j];
// B: lane holds B[k=quad*8+j][n=lane&15] (contiguous in Wt[n][k]); D: D[row=quad*4+reg][col=lane&15].
// Scores written NODE-MAJOR with stride SP: as_out[row*SP + h] (SP=8 for L1 so the
// head-merged attn kernel fetches all 5 heads' scores with one float4 + one scalar).
template<int NH, int SP, typename AT>
static __device__ __forceinline__ void gemm_phase(const AT* __restrict__ A,
                                                  const __half* __restrict__ Wt,
                                                  __half* __restrict__ C, int K,
                                                  const float* __restrict__ att_src,
                                                  const float* __restrict__ att_dst,
                                                  float* __restrict__ as_out,
                                                  float* __restrict__ ad_out,
                                                  int slot, int nsl, int lane) {
    const int N = NH * 64;
    int q = lane >> 4, l16 = lane & 15;
    for (int tile = slot; tile < N_NODES / 16; tile += nsl) {
        int rowBase = tile * 16;
        int arow = rowBase + l16;
        fx4 zero4 = {0.f, 0.f, 0.f, 0.f};
        fx4 acc[NH][4];
#pragma unroll
        for (int h = 0; h < NH; ++h)
#pragma unroll
            for (int c = 0; c < 4; ++c) acc[h][c] = zero4;
        for (int kk = 0; kk < K; kk += 32) {
            f16x8 af;
            if constexpr (std::is_same<AT, float>::value) {
                const float4* s = (const float4*)(A + (size_t)arow * K + kk + q * 8);
                float4 v0 = s[0], v1 = s[1];
                af[0] = (_Float16)v0.x; af[1] = (_Float16)v0.y;
                af[2] = (_Float16)v0.z; af[3] = (_Float16)v0.w;
                af[4] = (_Float16)v1.x; af[5] = (_Float16)v1.y;
                af[6] = (_Float16)v1.z; af[7] = (_Float16)v1.w;
            } else {
                af = *(const f16x8*)((const __half*)A + (size_t)arow * K + kk + q * 8);
            }
#pragma unroll
            for (int h = 0; h < NH; ++h) {
#pragma unroll
                for (int c = 0; c < 4; ++c) {
                    int col = h * 64 + c * 16 + l16;
                    f16x8 bf = *(const f16x8*)(Wt + (size_t)col * K + kk + q * 8);
                    acc[h][c] = __builtin_amdgcn_mfma_f32_16x16x32_f16(af, bf, acc[h][c], 0, 0, 0);
                }
            }
        }
#pragma unroll
        for (int h = 0; h < NH; ++h) {
            float ps[4] = {0.f, 0.f, 0.f, 0.f};
            float pd[4] = {0.f, 0.f, 0.f, 0.f};
#pragma unroll
            for (int c = 0; c < 4; ++c) {
                int gcol = h * 64 + c * 16 + l16;
                float av = att_src[gcol];
                float dv = att_dst[gcol];
#pragma unroll
                for (int reg = 0; reg < 4; ++reg) {
                    int grow = rowBase + q * 4 + reg;
                    float val = acc[h][c][reg];
                    C[(size_t)grow * N + gcol] = __float2half(val);
                    ps[reg] += val * av;
                    pd[reg] += val * dv;
                }
            }
#pragma unroll
            for (int off = 1; off < 16; off <<= 1) {
#pragma unroll
                for (int reg = 0; reg < 4; ++reg) {
                    ps[reg] += __shfl_xor(ps[reg], off, 64);
                    pd[reg] += __shfl_xor(pd[reg], off, 64);
                }
            }
            if (l16 == 0) {
#pragma unroll
                for (int reg = 0; reg < 4; ++reg) {
                    int grow = rowBase + q * 4 + reg;
                    as_out[(size_t)grow * SP + h] = ps[reg];
                    ad_out[(size_t)grow * SP + h] = pd[reg];
                }
            }
        }
    }
}

// ================ K0: seed self-loops || weight transpose/cast ================
// cnt is now written entirely by the K1 builder branch (dense, no atomics).
__global__ __launch_bounds__(256) void k_init(int* __restrict__ ovfc,
                                              int* __restrict__ esrc2,
                                              const float* __restrict__ W1,
                                              __half* __restrict__ Wt1,
                                              const float* __restrict__ W2,
                                              __half* __restrict__ Wt2) {
    int t = blockIdx.x * 256 + threadIdx.x;
    int nthr = gridDim.x * 256;
    for (int i = t; i < N_NODES; i += nthr) esrc2[i * BCAP] = i; // self-loop slot 0
    if (t == 0) *ovfc = 0;
    const int T1 = IN_CH * D1, T2 = D1 * OUT_CH;
    for (int idx = t; idx < T1 + T2; idx += nthr) {
        if (idx < T1) {
            int k = idx / D1, n = idx - k * D1;
            Wt1[(size_t)n * IN_CH + k] = __float2half(W1[idx]);
        } else {
            int i2 = idx - T1;
            int k = i2 / OUT_CH, n = i2 - k * OUT_CH;
            Wt2[(size_t)n * D1 + k] = __float2half(W2[i2]);
        }
    }
}

// ================ K1: layer-1 GEMM || atomic-free bucket build (node-range partitioned) ================
// GEMM branch FIRST (compiles to ~116 VGPR; bucket-first blew up to 256, R16).
// Builder: block pb owns nodes [pb*938, pb*938+938). It scans ALL 480K edges
// with int4 coalesced loads (edge array = 3.84MB, L2-resident; 32 blocks share
// per-XCD copies), keeps d in-range (~1.6% of lanes), assigns ranks via
// block-private LDS atomicAdd (exclusive ownership => deterministic, coherent),
// writes esrc2 slots directly, and finally writes dense cnt[n] = 1 + local count.
// The ONLY global atomic left is the (expected-zero) overflow append.
__global__ __launch_bounds__(256) void k_build_gemm1(const int* __restrict__ edge,
                                                     int* __restrict__ cnt,
                                                     int* __restrict__ esrc2,
                                                     int* __restrict__ ovf_cnt,
                                                     int* __restrict__ ovf,
                                                     const float* __restrict__ x,
                                                     const __half* __restrict__ Wt1,
                                                     __half* __restrict__ h1,
                                                     const float* __restrict__ att_src1,
                                                     const float* __restrict__ att_dst1,
                                                     float* __restrict__ as1,
                                                     float* __restrict__ ad1) {
    __shared__ int lcnt[NODES_PER_PB];
    int lane = threadIdx.x & 63, wv = threadIdx.x >> 6;
    if (blockIdx.x < GEMM1_BLOCKS) {
        gemm_phase<HEADS1, 8, float>(x, Wt1, h1, IN_CH, att_src1, att_dst1, as1, ad1,
                                     blockIdx.x * 4 + wv, GEMM1_BLOCKS * 4, lane);
    } else {
        int pb = blockIdx.x - GEMM1_BLOCKS;      // 0..31
        int lo = pb * NODES_PER_PB;
        int hi = lo + NODES_PER_PB;
        if (hi > N_NODES) hi = N_NODES;
        int range = hi - lo;
        for (int i = threadIdx.x; i < range; i += 256) lcnt[i] = 0;
        __syncthreads();
        for (int e = (threadIdx.x << 2); e < N_EDGES; e += 256 * 4) {
            int4 dd = *(const int4*)(edge + N_EDGES + e);
            int4 ss = *(const int4*)(edge + e);
            int dv[4] = {dd.x, dd.y, dd.z, dd.w};
            int sv[4] = {ss.x, ss.y, ss.z, ss.w};
#pragma unroll
            for (int u = 0; u < 4; ++u) {
                int d = dv[u];
                unsigned rel = (unsigned)(d - lo);
                if (rel < (unsigned)range) {
                    int rank = atomicAdd(&lcnt[rel], 1); // LDS atomic: ~free
                    if (rank < BCAP - 1) {
                        esrc2[(d << 6) + 1 + rank] = sv[u];
                    } else {
                        int oi = atomicAdd(ovf_cnt, 1);
                        ovf[2 * oi] = d;
                        ovf[2 * oi + 1] = sv[u];
                    }
                }
            }
        }
        __syncthreads();
        for (int i = threadIdx.x; i < range; i += 256)
            cnt[lo + i] = 1 + lcnt[i];
    }
}

// ================ head-merged softmax + aggregate — ONE WAVE PER NODE (R21-proven) ================
// One cnt load, one esrc2 gather, one j*RS; scores fetched for all heads at once
// (node-major [j][SP]); NH independent shuffle-reduce trees pipelined. Inner gather
// loop per head: lane = es*8+cg, 4 independent 16B loads, __hfma2, LDS pad-9
// transpose reduce.
template<int NH, bool RELU>
__global__ __launch_bounds__(256) void k_attn_agg(const int* __restrict__ cnt,
                                                  const int* __restrict__ esrc2,
                                                  const int* __restrict__ ovf_cnt,
                                                  const int* __restrict__ ovf,
                                                  const __half* __restrict__ hf,   // [N][NH*64]
                                                  const float* __restrict__ a_src, // [N][SP]
                                                  const float* __restrict__ a_dst, // [N][SP]
                                                  const float* __restrict__ bias,  // [NH*64]
                                                  __half* __restrict__ zout) {     // [N][NH*64]
    const int SP = (NH == 1) ? 1 : 8;
    __shared__ unsigned wpk[4][NH][64];
    __shared__ int jbuf[4][64];
    __shared__ float red[4][584];
    int node = (blockIdx.x * 256 + threadIdx.x) >> 6;
    int lane = threadIdx.x & 63;
    int wv = threadIdx.x >> 6;
    if (node >= N_NODES) return;
    int deg = cnt[node];
    const int RS = NH * 64;
    // dst-scores for this node (wave-uniform broadcast loads)
    float da[NH];
    if constexpr (NH == 1) {
        da[0] = a_dst[node];
    } else {
        float4 d0 = *(const float4*)(a_dst + (size_t)node * SP);
        da[0] = d0.x; da[1] = d0.y; da[2] = d0.z; da[3] = d0.w;
        da[4] = a_dst[(size_t)node * SP + 4];
    }
    if (deg <= BCAP) {
        int es = lane >> 3, cg = lane & 7;
        int joff = 0;
        float e[NH];
#pragma unroll
        for (int h = 0; h < NH; ++h) e[h] = 0.f;
        if (lane < deg) {
            int j = esrc2[node * BCAP + lane];
            joff = j * RS;
            if constexpr (NH == 1) {
                e[0] = __expf(leaky(a_src[j] + da[0]));
            } else {
                float4 s0 = *(const float4*)(a_src + (size_t)j * SP);
                float s4 = a_src[(size_t)j * SP + 4];
                e[0] = __expf(leaky(s0.x + da[0]));
                e[1] = __expf(leaky(s0.y + da[1]));
                e[2] = __expf(leaky(s0.z + da[2]));
                e[3] = __expf(leaky(s0.w + da[3]));
                e[4] = __expf(leaky(s4 + da[4]));
            }
        }
        float s[NH];
#pragma unroll
        for (int h = 0; h < NH; ++h) s[h] = e[h];
#pragma unroll
        for (int off = 1; off < 64; off <<= 1) {
#pragma unroll
            for (int h = 0; h < NH; ++h) s[h] += __shfl_xor(s[h], off, 64);
        }
#pragma unroll
        for (int h = 0; h < NH; ++h) {
            float r = 1.f / (s[h] + 1e-16f);
            __half2 wn = __float2half2_rn(e[h] * r);
            wpk[wv][h][lane] = *(unsigned*)&wn;
        }
        jbuf[wv][lane] = joff;
#pragma unroll
        for (int h = 0; h < NH; ++h) {
            const __half* hbase = hf + h * 64 + cg * 8;
            __half2 acch[4] = {__half2{0, 0}, __half2{0, 0}, __half2{0, 0}, __half2{0, 0}};
            for (int k0 = 0; k0 < deg; k0 += 32) {
                int kA = k0 + es, kB = kA + 8, kC = kA + 16, kD = kA + 24;
                unsigned uA = wpk[wv][h][kA];
                unsigned uB = wpk[wv][h][kB];
                unsigned uC = wpk[wv][h][kC];
                unsigned uD = wpk[wv][h][kD];
                int jA = jbuf[wv][kA];
                int jB = jbuf[wv][kB];
                int jC = jbuf[wv][kC];
                int jD = jbuf[wv][kD];
                float4 vA = *(const float4*)(hbase + jA);
                float4 vB = *(const float4*)(hbase + jB);
                float4 vC = *(const float4*)(hbase + jC);
                float4 vD = *(const float4*)(hbase + jD);
                __half2 hwA = *(__half2*)&uA, hwB = *(__half2*)&uB;
                __half2 hwC = *(__half2*)&uC, hwD = *(__half2*)&uD;
                const __half2* pA = (const __half2*)&vA;
                const __half2* pB = (const __half2*)&vB;
                const __half2* pC = (const __half2*)&vC;
                const __half2* pD = (const __half2*)&vD;
#pragma unroll
                for (int i = 0; i < 4; ++i) {
                    acch[i] = __hfma2(pA[i], hwA, acch[i]);
                    acch[i] = __hfma2(pB[i], hwB, acch[i]);
                    acch[i] = __hfma2(pC[i], hwC, acch[i]);
                    acch[i] = __hfma2(pD[i], hwD, acch[i]);
                }
            }
            // fp32 cross-es reduce via LDS pad-9 transpose (2-way conflicts = free)
#pragma unroll
            for (int i = 0; i < 4; ++i) {
                float2 f = __half22float2(acch[i]);
                red[wv][(cg * 8 + 2 * i) * 9 + es] = f.x;
                red[wv][(cg * 8 + 2 * i + 1) * 9 + es] = f.y;
            }
            float tot = 0.f;
#pragma unroll
            for (int e2 = 0; e2 < 8; ++e2)
                tot += red[wv][lane * 9 + e2];
            float o = tot + bias[h * 64 + lane];
            if (RELU) o = fmaxf(o, 0.f);
            zout[(size_t)node * RS + h * 64 + lane] = __float2half(o);
        }
    } else {
        // cold path: deg > BCAP. lane = channel; bucket (64 full) + overflow scan.
        int ovn = *ovf_cnt;
#pragma unroll
        for (int h = 0; h < NH; ++h) {
            float adsth = da[h];
            float sden = __expf(leaky(a_src[(size_t)esrc2[node * BCAP + lane] * SP + h] + adsth));
#pragma unroll
            for (int off = 1; off < 64; off <<= 1)
                sden += __shfl_xor(sden, off, 64);
            float s2 = 0.f;
            for (int k = lane; k < ovn; k += 64)
                if (ovf[2 * k] == node)
                    s2 += __expf(leaky(a_src[(size_t)ovf[2 * k + 1] * SP + h] + adsth));
#pragma unroll
            for (int off = 1; off < 64; off <<= 1)
                s2 += __shfl_xor(s2, off, 64);
            float r = 1.f / (sden + s2 + 1e-16f);
            float a = 0.f;
            for (int k = 0; k < BCAP; ++k) {
                int j = esrc2[node * BCAP + k];
                float w = __expf(leaky(a_src[(size_t)j * SP + h] + adsth));
                a += w * __half2float(hf[(size_t)j * RS + h * 64 + lane]);
            }
            for (int k = 0; k < ovn; ++k) {
                if (ovf[2 * k] == node) {
                    int j = ovf[2 * k + 1];
                    float w = __expf(leaky(a_src[(size_t)j * SP + h] + adsth));
                    a += w * __half2float(hf[(size_t)j * RS + h * 64 + lane]);
                }
            }
            float o = a * r + bias[h * 64 + lane];
            if (RELU) o = fmaxf(o, 0.f);
            zout[(size_t)node * RS + h * 64 + lane] = __float2half(o);
        }
    }
}

// ================ layer-2 GEMM (slot-strided, 256-thr blocks) ================
__global__ __launch_bounds__(256) void k_gemm2(const __half* __restrict__ z1,
                                               const __half* __restrict__ Wt2,
                                               __half* __restrict__ h2,
                                               const float* __restrict__ att_src2,
                                               const float* __restrict__ att_dst2,
                                               float* __restrict__ as2,
                                               float* __restrict__ ad2) {
    int lane = threadIdx.x & 63, wv = threadIdx.x >> 6;
    gemm_phase<1, 1, __half>(z1, Wt2, h2, D1, att_src2, att_dst2, as2, ad2,
                             blockIdx.x * 4 + wv, gridDim.x * 4, lane);
}

// ================ decode: 8 lanes per edge, 16B fp16 loads, fdot2 ================
__global__ __launch_bounds__(256) void k_decode(const int* __restrict__ pos,
                                                const int* __restrict__ neg,
                                                const __half* __restrict__ z2,
                                                float* __restrict__ out) {
    int t = blockIdx.x * 256 + threadIdx.x;
    int e = t >> 3;
    int lc = t & 7;
    if (e >= 2 * PE_CNT) return;
    int a, b;
    if (e < PE_CNT) { a = pos[e]; b = pos[PE_CNT + e]; }
    else { int k = e - PE_CNT; a = neg[k]; b = neg[PE_CNT + k]; }
    union U { float4 f; f16x2 h[4]; __half2 hh[4]; } ua, ub;
    ua.f = *(const float4*)(z2 + (size_t)a * OUT_CH + lc * 8);
    ub.f = *(const float4*)(z2 + (size_t)b * OUT_CH + lc * 8);
    float v = 0.f;
#pragma unroll
    for (int i = 0; i < 4; ++i) {
#ifdef HAS_FDOT2
        v = __builtin_amdgcn_fdot2(ua.h[i], ub.h[i], v, false);
#else
        float2 fa = __half22float2(ua.hh[i]);
        float2 fb = __half22float2(ub.hh[i]);
        v += fa.x * fb.x + fa.y * fb.y;
#endif
    }
#pragma unroll
    for (int off = 1; off < 8; off <<= 1)
        v += __shfl_xor(v, off, 64);
    if (lc == 0) out[e] = v;
}

extern "C" void kernel_launch(void* const* d_in, const int* in_sizes, int n_in,
                              void* d_out, int out_size, void* d_ws, size_t ws_size,
                              hipStream_t stream) {
    const float* x        = (const float*)d_in[0];
    const int* edge_index = (const int*)d_in[1];
    const int* pos_ei     = (const int*)d_in[2];
    const int* neg_ei     = (const int*)d_in[3];
    const float* W1       = (const float*)d_in[4];
    const float* att_src1 = (const float*)d_in[5];
    const float* att_dst1 = (const float*)d_in[6];
    const float* b1       = (const float*)d_in[7];
    const float* W2       = (const float*)d_in[8];
    const float* att_src2 = (const float*)d_in[9];
    const float* att_dst2 = (const float*)d_in[10];
    const float* b2       = (const float*)d_in[11];
    float* out            = (float*)d_out;

    char* ws = (char*)d_ws;
    size_t off = 0;
    auto alloc = [&](size_t bytes) -> void* {
        void* p = ws + off;
        off = (off + bytes + 255) & ~(size_t)255;
        return p;
    };
    int* cnt     = (int*)alloc(sizeof(int) * N_NODES);   // dense again (no atomics on it)
    int* ovfc    = (int*)alloc(sizeof(int) * 8);
    int* esrc2   = (int*)alloc(sizeof(int) * (size_t)N_NODES * BCAP);
    int* ovf     = (int*)alloc(sizeof(int) * (size_t)2 * N_EDGES_SL);
    __half* h1   = (__half*)alloc(sizeof(__half) * (size_t)N_NODES * D1);
    __half* z1   = (__half*)alloc(sizeof(__half) * (size_t)N_NODES * D1);
    __half* h2   = (__half*)alloc(sizeof(__half) * (size_t)N_NODES * OUT_CH);
    __half* z2   = (__half*)alloc(sizeof(__half) * (size_t)N_NODES * OUT_CH);
    __half* Wt1  = (__half*)alloc(sizeof(__half) * (size_t)D1 * IN_CH);
    __half* Wt2  = (__half*)alloc(sizeof(__half) * (size_t)OUT_CH * D1);
    float* as1   = (float*)alloc(sizeof(float) * (size_t)N_NODES * 8); // [N][8] node-major, 5 used
    float* ad1   = (float*)alloc(sizeof(float) * (size_t)N_NODES * 8); // [N][8]
    float* as2   = (float*)alloc(sizeof(float) * (size_t)N_NODES);
    float* ad2   = (float*)alloc(sizeof(float) * (size_t)N_NODES);

    // K0: seed self-loops || weight prep
    k_init<<<240, 256, 0, stream>>>(ovfc, esrc2, W1, Wt1, W2, Wt2);
    // K1: layer-1 MFMA GEMM + scores || atomic-free bucket build (one pass, block-split)
    k_build_gemm1<<<GEMM1_BLOCKS + PASS_BLOCKS, 256, 0, stream>>>(
        edge_index, cnt, esrc2, ovfc, ovf, x, Wt1, h1, att_src1, att_dst1, as1, ad1);
    // K2: layer-1 softmax-aggregate (+relu) — one wave per node, 5 heads merged
    k_attn_agg<HEADS1, true><<<(N_NODES + 3) / 4, 256, 0, stream>>>(
        cnt, esrc2, ovfc, ovf, h1, as1, ad1, b1, z1);
    // K3: layer-2 GEMM + scores
    k_gemm2<<<469, 256, 0, stream>>>(z1, Wt2, h2, att_src2, att_dst2, as2, ad2);
    // K4: layer-2 softmax-aggregate
    k_attn_agg<1, false><<<(N_NODES + 3) / 4, 256, 0, stream>>>(
        cnt, esrc2, ovfc, ovf, h2, as2, ad2, b2, z2);
    // K5: decode
    k_decode<<<(2 * PE_CNT * 8 + 255) / 256, 256, 0, stream>>>(pos_ei, neg_ei, z2, out);

    (void)in_sizes; (void)n_in; (void)out_size; (void)ws_size;
}

// Round 4
// 259.983 us; speedup vs baseline: 1.7942x; 1.7942x over previous
//
#include <hip/hip_runtime.h>
#include <hip/hip_fp16.h>
#include <cstdint>
#include <cstddef>
#include <type_traits>

#define N_NODES 30000
#define N_EDGES 480000
#define N_EDGES_SL (N_EDGES + N_NODES) // 510000
#define IN_CH 128
#define HEADS1 5
#define C1 64
#define D1 (HEADS1 * C1) // 320
#define OUT_CH 64
#define PE_CNT 100000
#define NEG_SLOPE 0.2f
#define BCAP 64   // 64 slots per node: slot = rank*4 + subrange (striped)
#define GEMM1_BLOCKS 469
#define NPART 32            // node-range partitions
#define ESR 4               // edge subranges
#define BUILD_BLOCKS (NPART * ESR) // 128
#define NODES_PER_PB ((N_NODES + NPART - 1) / NPART) // 938
#define ESUB (N_EDGES / ESR) // 120000
#define SLOT_MAX 16         // ranks 0..15 per subrange fit in bucket; >=16 -> overflow
// R23: atomic-free CSR build, second attempt. R22 (32 blocks x full-edge scan)
// was latency-starved: 469 serial iters/block, 3% occupancy, 330us. Fix: 2D
// partition (32 node-ranges x 4 edge-subranges = 128 blocks, 30 iters each,
// 16 edges/thread phase-separated). Subranges write disjoint striped slots
// (slot = rank*4 + r) ranked by block-private LDS counters -> zero rank
// coordination. Global returning atomics (the R19-R21-proven ~8/ns cap,
// 60us floor) remain eliminated; overflow list is p~2e-7 dead code.

typedef _Float16 f16x8 __attribute__((ext_vector_type(8)));
typedef _Float16 f16x2 __attribute__((ext_vector_type(2)));
typedef float fx4 __attribute__((ext_vector_type(4)));

#if defined(__has_builtin)
#if __has_builtin(__builtin_amdgcn_fdot2)
#define HAS_FDOT2 1
#endif
#endif

static __device__ __forceinline__ float leaky(float x) {
    return fmaxf(x, NEG_SLOPE * x); // valid for 0<slope<1
}

// ---------------- barrier-free MFMA fp16 GEMM phase + fused attention scores ----------------
// Wave-slot per 16-row tile (30000 = 16*1875). No LDS, no barriers.
// mfma_f32_16x16x32_f16 layouts (HW-verified): A: lane holds A[m=lane&15][k=quad*8+j];
// B: lane holds B[k=quad*8+j][n=lane&15] (contiguous in Wt[n][k]); D: D[row=quad*4+reg][col=lane&15].
// Scores written NODE-MAJOR with stride SP: as_out[row*SP + h].
template<int NH, int SP, typename AT>
static __device__ __forceinline__ void gemm_phase(const AT* __restrict__ A,
                                                  const __half* __restrict__ Wt,
                                                  __half* __restrict__ C, int K,
                                                  const float* __restrict__ att_src,
                                                  const float* __restrict__ att_dst,
                                                  float* __restrict__ as_out,
                                                  float* __restrict__ ad_out,
                                                  int slot, int nsl, int lane) {
    const int N = NH * 64;
    int q = lane >> 4, l16 = lane & 15;
    for (int tile = slot; tile < N_NODES / 16; tile += nsl) {
        int rowBase = tile * 16;
        int arow = rowBase + l16;
        fx4 zero4 = {0.f, 0.f, 0.f, 0.f};
        fx4 acc[NH][4];
#pragma unroll
        for (int h = 0; h < NH; ++h)
#pragma unroll
            for (int c = 0; c < 4; ++c) acc[h][c] = zero4;
        for (int kk = 0; kk < K; kk += 32) {
            f16x8 af;
            if constexpr (std::is_same<AT, float>::value) {
                const float4* s = (const float4*)(A + (size_t)arow * K + kk + q * 8);
                float4 v0 = s[0], v1 = s[1];
                af[0] = (_Float16)v0.x; af[1] = (_Float16)v0.y;
                af[2] = (_Float16)v0.z; af[3] = (_Float16)v0.w;
                af[4] = (_Float16)v1.x; af[5] = (_Float16)v1.y;
                af[6] = (_Float16)v1.z; af[7] = (_Float16)v1.w;
            } else {
                af = *(const f16x8*)((const __half*)A + (size_t)arow * K + kk + q * 8);
            }
#pragma unroll
            for (int h = 0; h < NH; ++h) {
#pragma unroll
                for (int c = 0; c < 4; ++c) {
                    int col = h * 64 + c * 16 + l16;
                    f16x8 bf = *(const f16x8*)(Wt + (size_t)col * K + kk + q * 8);
                    acc[h][c] = __builtin_amdgcn_mfma_f32_16x16x32_f16(af, bf, acc[h][c], 0, 0, 0);
                }
            }
        }
#pragma unroll
        for (int h = 0; h < NH; ++h) {
            float ps[4] = {0.f, 0.f, 0.f, 0.f};
            float pd[4] = {0.f, 0.f, 0.f, 0.f};
#pragma unroll
            for (int c = 0; c < 4; ++c) {
                int gcol = h * 64 + c * 16 + l16;
                float av = att_src[gcol];
                float dv = att_dst[gcol];
#pragma unroll
                for (int reg = 0; reg < 4; ++reg) {
                    int grow = rowBase + q * 4 + reg;
                    float val = acc[h][c][reg];
                    C[(size_t)grow * N + gcol] = __float2half(val);
                    ps[reg] += val * av;
                    pd[reg] += val * dv;
                }
            }
#pragma unroll
            for (int off = 1; off < 16; off <<= 1) {
#pragma unroll
                for (int reg = 0; reg < 4; ++reg) {
                    ps[reg] += __shfl_xor(ps[reg], off, 64);
                    pd[reg] += __shfl_xor(pd[reg], off, 64);
                }
            }
            if (l16 == 0) {
#pragma unroll
                for (int reg = 0; reg < 4; ++reg) {
                    int grow = rowBase + q * 4 + reg;
                    as_out[(size_t)grow * SP + h] = ps[reg];
                    ad_out[(size_t)grow * SP + h] = pd[reg];
                }
            }
        }
    }
}

// ================ K0: seed self-loops || weight transpose/cast ================
__global__ __launch_bounds__(256) void k_init(int* __restrict__ ovfc,
                                              int* __restrict__ esrc2,
                                              const float* __restrict__ W1,
                                              __half* __restrict__ Wt1,
                                              const float* __restrict__ W2,
                                              __half* __restrict__ Wt2) {
    int t = blockIdx.x * 256 + threadIdx.x;
    int nthr = gridDim.x * 256;
    for (int i = t; i < N_NODES; i += nthr) esrc2[i * BCAP] = i; // self-loop = slot 0 (rank0,sub0)
    if (t == 0) *ovfc = 0;
    const int T1 = IN_CH * D1, T2 = D1 * OUT_CH;
    for (int idx = t; idx < T1 + T2; idx += nthr) {
        if (idx < T1) {
            int k = idx / D1, n = idx - k * D1;
            Wt1[(size_t)n * IN_CH + k] = __float2half(W1[idx]);
        } else {
            int i2 = idx - T1;
            int k = i2 / OUT_CH, n = i2 - k * OUT_CH;
            Wt2[(size_t)n * D1 + k] = __float2half(W2[i2]);
        }
    }
}

// ================ K1: layer-1 GEMM || atomic-free striped-slot CSR build ================
// GEMM branch FIRST (116-VGPR ordering, R15/R16-proven). Builder block b:
// node-partition p = b>>2 owns nodes [p*938, p*938+938); edge-subrange r = b&3
// owns edges [r*120K, (r+1)*120K) and slots {i*4+r} of each node's bucket.
// 30 iterations of 16 edges/thread: 8 coalesced int4 loads issued together
// (phase-separated ILP), then 16 exec-masked LDS-rank inserts. Fill counts
// written dense to cnts[r][node]. Only global atomic: ~never-taken overflow.
__global__ __launch_bounds__(256) void k_build_gemm1(const int* __restrict__ edge,
                                                     int* __restrict__ cnts,
                                                     int* __restrict__ esrc2,
                                                     int* __restrict__ ovf_cnt,
                                                     int* __restrict__ ovf,
                                                     const float* __restrict__ x,
                                                     const __half* __restrict__ Wt1,
                                                     __half* __restrict__ h1,
                                                     const float* __restrict__ att_src1,
                                                     const float* __restrict__ att_dst1,
                                                     float* __restrict__ as1,
                                                     float* __restrict__ ad1) {
    __shared__ int lcnt[NODES_PER_PB];
    int lane = threadIdx.x & 63, wv = threadIdx.x >> 6;
    if (blockIdx.x < GEMM1_BLOCKS) {
        gemm_phase<HEADS1, 8, float>(x, Wt1, h1, IN_CH, att_src1, att_dst1, as1, ad1,
                                     blockIdx.x * 4 + wv, GEMM1_BLOCKS * 4, lane);
    } else {
        int b = blockIdx.x - GEMM1_BLOCKS;   // 0..127
        int p = b >> 2, r = b & 3;
        int lo = p * NODES_PER_PB;
        int hi = lo + NODES_PER_PB;
        if (hi > N_NODES) hi = N_NODES;
        int range = hi - lo;
        int seed = (r == 0) ? 1 : 0;         // self-loop = rank 0 of subrange 0
        for (int i = threadIdx.x; i < range; i += 256) lcnt[i] = seed;
        __syncthreads();
        const int sub1 = (r + 1) * ESUB;
        for (int base = r * ESUB; base < sub1; base += 4096) {
            int4 dd[4], ss[4];
#pragma unroll
            for (int k = 0; k < 4; ++k) {
                int e4 = base + ((k << 8) + (int)threadIdx.x) * 4;
                if (e4 < sub1) {
                    dd[k] = *(const int4*)(edge + N_EDGES + e4);
                    ss[k] = *(const int4*)(edge + e4);
                } else {
                    dd[k] = int4{-1, -1, -1, -1};
                    ss[k] = int4{0, 0, 0, 0};
                }
            }
#pragma unroll
            for (int k = 0; k < 4; ++k) {
                int dv[4] = {dd[k].x, dd[k].y, dd[k].z, dd[k].w};
                int sv[4] = {ss[k].x, ss[k].y, ss[k].z, ss[k].w};
#pragma unroll
                for (int u = 0; u < 4; ++u) {
                    unsigned rel = (unsigned)(dv[u] - lo);
                    if (rel < (unsigned)range) {
                        int rk = atomicAdd(&lcnt[rel], 1); // LDS atomic, block-private
                        if (rk < SLOT_MAX) {
                            esrc2[(dv[u] << 6) + (rk << 2) + r] = sv[u];
                        } else {
                            int oi = atomicAdd(ovf_cnt, 1);
                            ovf[2 * oi] = dv[u];
                            ovf[2 * oi + 1] = sv[u];
                        }
                    }
                }
            }
        }
        __syncthreads();
        for (int i = threadIdx.x; i < range; i += 256)
            cnts[r * N_NODES + lo + i] = lcnt[i];
    }
}

// ================ head-merged softmax + aggregate — ONE WAVE PER NODE (R21-proven) ================
// Striped-slot validity: lane l owns slot l = rank(l>>2) of subrange (l&3);
// valid iff rank < fill[l&3]. Invalid slots carry weight 0 (identical math to
// the old lane<deg predicate). Gather runs 1 chunk when maxfill<=8 (~90% of
// nodes), 2 otherwise. Cold path triggers iff any fill > 16 (=> overflow list
// non-empty for this node), p~2e-7.
template<int NH, bool RELU>
__global__ __launch_bounds__(256) void k_attn_agg(const int* __restrict__ cnts,
                                                  const int* __restrict__ esrc2,
                                                  const int* __restrict__ ovf_cnt,
                                                  const int* __restrict__ ovf,
                                                  const __half* __restrict__ hf,   // [N][NH*64]
                                                  const float* __restrict__ a_src, // [N][SP]
                                                  const float* __restrict__ a_dst, // [N][SP]
                                                  const float* __restrict__ bias,  // [NH*64]
                                                  __half* __restrict__ zout) {     // [N][NH*64]
    const int SP = (NH == 1) ? 1 : 8;
    __shared__ unsigned wpk[4][NH][64];
    __shared__ int jbuf[4][64];
    __shared__ float red[4][584];
    int node = (blockIdx.x * 256 + threadIdx.x) >> 6;
    int lane = threadIdx.x & 63;
    int wv = threadIdx.x >> 6;
    if (node >= N_NODES) return;
    const int RS = NH * 64;
    int fl = cnts[(lane & 3) * N_NODES + node];
    int mf = max(fl, __shfl_xor(fl, 1, 64));
    mf = max(mf, __shfl_xor(mf, 2, 64));
    // dst-scores for this node (wave-uniform broadcast loads)
    float da[NH];
    if constexpr (NH == 1) {
        da[0] = a_dst[node];
    } else {
        float4 d0 = *(const float4*)(a_dst + (size_t)node * SP);
        da[0] = d0.x; da[1] = d0.y; da[2] = d0.z; da[3] = d0.w;
        da[4] = a_dst[(size_t)node * SP + 4];
    }
    if (mf <= SLOT_MAX) {
        int es = lane >> 3, cg = lane & 7;
        bool valid = (lane >> 2) < fl;
        int joff = 0;
        float e[NH];
#pragma unroll
        for (int h = 0; h < NH; ++h) e[h] = 0.f;
        if (valid) {
            int j = esrc2[node * BCAP + lane];
            joff = j * RS;
            if constexpr (NH == 1) {
                e[0] = __expf(leaky(a_src[j] + da[0]));
            } else {
                float4 s0 = *(const float4*)(a_src + (size_t)j * SP);
                float s4 = a_src[(size_t)j * SP + 4];
                e[0] = __expf(leaky(s0.x + da[0]));
                e[1] = __expf(leaky(s0.y + da[1]));
                e[2] = __expf(leaky(s0.z + da[2]));
                e[3] = __expf(leaky(s0.w + da[3]));
                e[4] = __expf(leaky(s4 + da[4]));
            }
        }
        float s[NH];
#pragma unroll
        for (int h = 0; h < NH; ++h) s[h] = e[h];
#pragma unroll
        for (int off = 1; off < 64; off <<= 1) {
#pragma unroll
            for (int h = 0; h < NH; ++h) s[h] += __shfl_xor(s[h], off, 64);
        }
#pragma unroll
        for (int h = 0; h < NH; ++h) {
            float r = 1.f / (s[h] + 1e-16f);
            __half2 wn = __float2half2_rn(e[h] * r);
            wpk[wv][h][lane] = *(unsigned*)&wn;
        }
        jbuf[wv][lane] = joff;
        int kmax = (mf > 8) ? 64 : 32;
#pragma unroll
        for (int h = 0; h < NH; ++h) {
            const __half* hbase = hf + h * 64 + cg * 8;
            __half2 acch[4] = {__half2{0, 0}, __half2{0, 0}, __half2{0, 0}, __half2{0, 0}};
            for (int k0 = 0; k0 < kmax; k0 += 32) {
                int kA = k0 + es, kB = kA + 8, kC = kA + 16, kD = kA + 24;
                unsigned uA = wpk[wv][h][kA];
                unsigned uB = wpk[wv][h][kB];
                unsigned uC = wpk[wv][h][kC];
                unsigned uD = wpk[wv][h][kD];
                int jA = jbuf[wv][kA];
                int jB = jbuf[wv][kB];
                int jC = jbuf[wv][kC];
                int jD = jbuf[wv][kD];
                float4 vA = *(const float4*)(hbase + jA);
                float4 vB = *(const float4*)(hbase + jB);
                float4 vC = *(const float4*)(hbase + jC);
                float4 vD = *(const float4*)(hbase + jD);
                __half2 hwA = *(__half2*)&uA, hwB = *(__half2*)&uB;
                __half2 hwC = *(__half2*)&uC, hwD = *(__half2*)&uD;
                const __half2* pA = (const __half2*)&vA;
                const __half2* pB = (const __half2*)&vB;
                const __half2* pC = (const __half2*)&vC;
                const __half2* pD = (const __half2*)&vD;
#pragma unroll
                for (int i = 0; i < 4; ++i) {
                    acch[i] = __hfma2(pA[i], hwA, acch[i]);
                    acch[i] = __hfma2(pB[i], hwB, acch[i]);
                    acch[i] = __hfma2(pC[i], hwC, acch[i]);
                    acch[i] = __hfma2(pD[i], hwD, acch[i]);
                }
            }
            // fp32 cross-es reduce via LDS pad-9 transpose (2-way conflicts = free)
#pragma unroll
            for (int i = 0; i < 4; ++i) {
                float2 f = __half22float2(acch[i]);
                red[wv][(cg * 8 + 2 * i) * 9 + es] = f.x;
                red[wv][(cg * 8 + 2 * i + 1) * 9 + es] = f.y;
            }
            float tot = 0.f;
#pragma unroll
            for (int e2 = 0; e2 < 8; ++e2)
                tot += red[wv][lane * 9 + e2];
            float o = tot + bias[h * 64 + lane];
            if (RELU) o = fmaxf(o, 0.f);
            zout[(size_t)node * RS + h * 64 + lane] = __float2half(o);
        }
    } else {
        // cold path (fill > 16 somewhere): lane = channel, scalar slot scan + overflow list.
        int ovn = *ovf_cnt;
        int f[4];
#pragma unroll
        for (int rr = 0; rr < 4; ++rr) f[rr] = min(cnts[rr * N_NODES + node], SLOT_MAX);
#pragma unroll
        for (int h = 0; h < NH; ++h) {
            float adsth = da[h];
            float sden = 0.f, a = 0.f;
            for (int k = 0; k < BCAP; ++k) {
                int rr = k & 3, ii = k >> 2;
                if (ii < f[rr]) {
                    int j = esrc2[node * BCAP + k];
                    float w = __expf(leaky(a_src[(size_t)j * SP + h] + adsth));
                    sden += w;
                    a += w * __half2float(hf[(size_t)j * RS + h * 64 + lane]);
                }
            }
            for (int k = 0; k < ovn; ++k) {
                if (ovf[2 * k] == node) {
                    int j = ovf[2 * k + 1];
                    float w = __expf(leaky(a_src[(size_t)j * SP + h] + adsth));
                    sden += w;
                    a += w * __half2float(hf[(size_t)j * RS + h * 64 + lane]);
                }
            }
            float o = a / (sden + 1e-16f) + bias[h * 64 + lane];
            if (RELU) o = fmaxf(o, 0.f);
            zout[(size_t)node * RS + h * 64 + lane] = __float2half(o);
        }
    }
}

// ================ layer-2 GEMM (slot-strided, 256-thr blocks) ================
__global__ __launch_bounds__(256) void k_gemm2(const __half* __restrict__ z1,
                                               const __half* __restrict__ Wt2,
                                               __half* __restrict__ h2,
                                               const float* __restrict__ att_src2,
                                               const float* __restrict__ att_dst2,
                                               float* __restrict__ as2,
                                               float* __restrict__ ad2) {
    int lane = threadIdx.x & 63, wv = threadIdx.x >> 6;
    gemm_phase<1, 1, __half>(z1, Wt2, h2, D1, att_src2, att_dst2, as2, ad2,
                             blockIdx.x * 4 + wv, gridDim.x * 4, lane);
}

// ================ decode: 8 lanes per edge, 16B fp16 loads, fdot2 ================
__global__ __launch_bounds__(256) void k_decode(const int* __restrict__ pos,
                                                const int* __restrict__ neg,
                                                const __half* __restrict__ z2,
                                                float* __restrict__ out) {
    int t = blockIdx.x * 256 + threadIdx.x;
    int e = t >> 3;
    int lc = t & 7;
    if (e >= 2 * PE_CNT) return;
    int a, b;
    if (e < PE_CNT) { a = pos[e]; b = pos[PE_CNT + e]; }
    else { int k = e - PE_CNT; a = neg[k]; b = neg[PE_CNT + k]; }
    union U { float4 f; f16x2 h[4]; __half2 hh[4]; } ua, ub;
    ua.f = *(const float4*)(z2 + (size_t)a * OUT_CH + lc * 8);
    ub.f = *(const float4*)(z2 + (size_t)b * OUT_CH + lc * 8);
    float v = 0.f;
#pragma unroll
    for (int i = 0; i < 4; ++i) {
#ifdef HAS_FDOT2
        v = __builtin_amdgcn_fdot2(ua.h[i], ub.h[i], v, false);
#else
        float2 fa = __half22float2(ua.hh[i]);
        float2 fb = __half22float2(ub.hh[i]);
        v += fa.x * fb.x + fa.y * fb.y;
#endif
    }
#pragma unroll
    for (int off = 1; off < 8; off <<= 1)
        v += __shfl_xor(v, off, 64);
    if (lc == 0) out[e] = v;
}

extern "C" void kernel_launch(void* const* d_in, const int* in_sizes, int n_in,
                              void* d_out, int out_size, void* d_ws, size_t ws_size,
                              hipStream_t stream) {
    const float* x        = (const float*)d_in[0];
    const int* edge_index = (const int*)d_in[1];
    const int* pos_ei     = (const int*)d_in[2];
    const int* neg_ei     = (const int*)d_in[3];
    const float* W1       = (const float*)d_in[4];
    const float* att_src1 = (const float*)d_in[5];
    const float* att_dst1 = (const float*)d_in[6];
    const float* b1       = (const float*)d_in[7];
    const float* W2       = (const float*)d_in[8];
    const float* att_src2 = (const float*)d_in[9];
    const float* att_dst2 = (const float*)d_in[10];
    const float* b2       = (const float*)d_in[11];
    float* out            = (float*)d_out;

    char* ws = (char*)d_ws;
    size_t off = 0;
    auto alloc = [&](size_t bytes) -> void* {
        void* p = ws + off;
        off = (off + bytes + 255) & ~(size_t)255;
        return p;
    };
    int* cnts    = (int*)alloc(sizeof(int) * (size_t)ESR * N_NODES); // [4][N] fill counts
    int* ovfc    = (int*)alloc(sizeof(int) * 8);
    int* esrc2   = (int*)alloc(sizeof(int) * (size_t)N_NODES * BCAP);
    int* ovf     = (int*)alloc(sizeof(int) * (size_t)2 * N_EDGES_SL);
    __half* h1   = (__half*)alloc(sizeof(__half) * (size_t)N_NODES * D1);
    __half* z1   = (__half*)alloc(sizeof(__half) * (size_t)N_NODES * D1);
    __half* h2   = (__half*)alloc(sizeof(__half) * (size_t)N_NODES * OUT_CH);
    __half* z2   = (__half*)alloc(sizeof(__half) * (size_t)N_NODES * OUT_CH);
    __half* Wt1  = (__half*)alloc(sizeof(__half) * (size_t)D1 * IN_CH);
    __half* Wt2  = (__half*)alloc(sizeof(__half) * (size_t)OUT_CH * D1);
    float* as1   = (float*)alloc(sizeof(float) * (size_t)N_NODES * 8); // [N][8] node-major, 5 used
    float* ad1   = (float*)alloc(sizeof(float) * (size_t)N_NODES * 8); // [N][8]
    float* as2   = (float*)alloc(sizeof(float) * (size_t)N_NODES);
    float* ad2   = (float*)alloc(sizeof(float) * (size_t)N_NODES);

    // K0: seed self-loops || weight prep
    k_init<<<240, 256, 0, stream>>>(ovfc, esrc2, W1, Wt1, W2, Wt2);
    // K1: layer-1 MFMA GEMM + scores || atomic-free striped-slot CSR build
    k_build_gemm1<<<GEMM1_BLOCKS + BUILD_BLOCKS, 256, 0, stream>>>(
        edge_index, cnts, esrc2, ovfc, ovf, x, Wt1, h1, att_src1, att_dst1, as1, ad1);
    // K2: layer-1 softmax-aggregate (+relu) — one wave per node, 5 heads merged
    k_attn_agg<HEADS1, true><<<(N_NODES + 3) / 4, 256, 0, stream>>>(
        cnts, esrc2, ovfc, ovf, h1, as1, ad1, b1, z1);
    // K3: layer-2 GEMM + scores
    k_gemm2<<<469, 256, 0, stream>>>(z1, Wt2, h2, att_src2, att_dst2, as2, ad2);
    // K4: layer-2 softmax-aggregate
    k_attn_agg<1, false><<<(N_NODES + 3) / 4, 256, 0, stream>>>(
        cnts, esrc2, ovfc, ovf, h2, as2, ad2, b2, z2);
    // K5: decode
    k_decode<<<(2 * PE_CNT * 8 + 255) / 256, 256, 0, stream>>>(pos_ei, neg_ei, z2, out);

    (void)in_sizes; (void)n_in; (void)out_size; (void)ws_size;
}

// Round 6
// 207.457 us; speedup vs baseline: 2.2484x; 1.2532x over previous
//
#include <hip/hip_runtime.h>
#include <hip/hip_fp16.h>
#include <cstdint>
#include <cstddef>
#include <type_traits>

#define N_NODES 30000
#define N_EDGES 480000
#define N_EDGES_SL (N_EDGES + N_NODES) // 510000
#define IN_CH 128
#define HEADS1 5
#define C1 64
#define D1 (HEADS1 * C1) // 320
#define OUT_CH 64
#define PE_CNT 100000
#define NEG_SLOPE 0.2f
#define BCAP 64   // bucket: slot 0 = self-loop, slots 1..deg = edges (exact global ranks)
#define GEMM1_BLOCKS 469
#define INIT_BLOCKS 240
#define BB 120              // builder blocks (pass A / pass B)
#define EPB (N_EDGES / BB)  // 4000 edges per builder block (exact)
#define NW (N_NODES / 2)    // 15000 packed u32 words (2 x u16 bins per word)
#define PFX_BLOCKS 59       // prefix blocks: 59*256 = 15104 >= NW
#define OVF_CAP 65536       // overflow list capacity (writes clamped; p(use)~1e-18)
// R25 = R24 (two-pass counting-sort CSR build) with the workspace overflow fixed.
// R24's container crash: total ws hit 74.6MB; every passing round was <64.0MB
// (R21 = 63.97MB) -> ws_size is ~64MB and the tail buffers (as1/ad1, written by
// every GEMM wave) landed out-of-bounds. Fix: partA/offA alias z1's 19.2MB
// (dead after k_rank, which stream-orders before K2's first z1 write) and ovf
// shrinks 4.08MB -> 512KB capped. New total ~56.7MB.
// Build scheme (R24): each edge visited exactly twice, by exactly one block,
// all 64 lanes active, zero global returning atomics (R19/R20/R21 proved that
// path is capped ~8/ns = 60us floor):
//   passA (in K0): per-block LDS histogram of own 4000 edges -> partA[b][w]
//   prefix (in K1, beside GEMM): exclusive prefix over blocks -> offA, cnt
//   passB (k_rank): local rank via LDS atomicAdd-return; slot = off + lr.
// Bins packed 2 nodes/u32 (count<=4000 fits u16, no carry) -> 60KB static LDS.
// offA clamped at 64: slot = off+lr >= 64 <=> true rank >= 64 -> overflow list.

typedef _Float16 f16x8 __attribute__((ext_vector_type(8)));
typedef _Float16 f16x2 __attribute__((ext_vector_type(2)));
typedef float fx4 __attribute__((ext_vector_type(4)));

#if defined(__has_builtin)
#if __has_builtin(__builtin_amdgcn_fdot2)
#define HAS_FDOT2 1
#endif
#endif

static __device__ __forceinline__ float leaky(float x) {
    return fmaxf(x, NEG_SLOPE * x); // valid for 0<slope<1
}

// ---------------- barrier-free MFMA fp16 GEMM phase + fused attention scores ----------------
// Wave-slot per 16-row tile (30000 = 16*1875). No LDS, no barriers.
// mfma_f32_16x16x32_f16 layouts (HW-verified): A: lane holds A[m=lane&15][k=quad*8+j];
// B: lane holds B[k=quad*8+j][n=lane&15] (contiguous in Wt[n][k]); D: D[row=quad*4+reg][col=lane&15].
// Scores written NODE-MAJOR with stride SP: as_out[row*SP + h].
template<int NH, int SP, typename AT>
static __device__ __forceinline__ void gemm_phase(const AT* __restrict__ A,
                                                  const __half* __restrict__ Wt,
                                                  __half* __restrict__ C, int K,
                                                  const float* __restrict__ att_src,
                                                  const float* __restrict__ att_dst,
                                                  float* __restrict__ as_out,
                                                  float* __restrict__ ad_out,
                                                  int slot, int nsl, int lane) {
    const int N = NH * 64;
    int q = lane >> 4, l16 = lane & 15;
    for (int tile = slot; tile < N_NODES / 16; tile += nsl) {
        int rowBase = tile * 16;
        int arow = rowBase + l16;
        fx4 zero4 = {0.f, 0.f, 0.f, 0.f};
        fx4 acc[NH][4];
#pragma unroll
        for (int h = 0; h < NH; ++h)
#pragma unroll
            for (int c = 0; c < 4; ++c) acc[h][c] = zero4;
        for (int kk = 0; kk < K; kk += 32) {
            f16x8 af;
            if constexpr (std::is_same<AT, float>::value) {
                const float4* s = (const float4*)(A + (size_t)arow * K + kk + q * 8);
                float4 v0 = s[0], v1 = s[1];
                af[0] = (_Float16)v0.x; af[1] = (_Float16)v0.y;
                af[2] = (_Float16)v0.z; af[3] = (_Float16)v0.w;
                af[4] = (_Float16)v1.x; af[5] = (_Float16)v1.y;
                af[6] = (_Float16)v1.z; af[7] = (_Float16)v1.w;
            } else {
                af = *(const f16x8*)((const __half*)A + (size_t)arow * K + kk + q * 8);
            }
#pragma unroll
            for (int h = 0; h < NH; ++h) {
#pragma unroll
                for (int c = 0; c < 4; ++c) {
                    int col = h * 64 + c * 16 + l16;
                    f16x8 bf = *(const f16x8*)(Wt + (size_t)col * K + kk + q * 8);
                    acc[h][c] = __builtin_amdgcn_mfma_f32_16x16x32_f16(af, bf, acc[h][c], 0, 0, 0);
                }
            }
        }
#pragma unroll
        for (int h = 0; h < NH; ++h) {
            float ps[4] = {0.f, 0.f, 0.f, 0.f};
            float pd[4] = {0.f, 0.f, 0.f, 0.f};
#pragma unroll
            for (int c = 0; c < 4; ++c) {
                int gcol = h * 64 + c * 16 + l16;
                float av = att_src[gcol];
                float dv = att_dst[gcol];
#pragma unroll
                for (int reg = 0; reg < 4; ++reg) {
                    int grow = rowBase + q * 4 + reg;
                    float val = acc[h][c][reg];
                    C[(size_t)grow * N + gcol] = __float2half(val);
                    ps[reg] += val * av;
                    pd[reg] += val * dv;
                }
            }
#pragma unroll
            for (int off = 1; off < 16; off <<= 1) {
#pragma unroll
                for (int reg = 0; reg < 4; ++reg) {
                    ps[reg] += __shfl_xor(ps[reg], off, 64);
                    pd[reg] += __shfl_xor(pd[reg], off, 64);
                }
            }
            if (l16 == 0) {
#pragma unroll
                for (int reg = 0; reg < 4; ++reg) {
                    int grow = rowBase + q * 4 + reg;
                    as_out[(size_t)grow * SP + h] = ps[reg];
                    ad_out[(size_t)grow * SP + h] = pd[reg];
                }
            }
        }
    }
}

// ================ K0: init (self-loops, ovfc, weight transpose) || pass A histogram ================
// Blocks [0,240): init. Blocks [240,360): builder block b = blockIdx-240 histograms
// its 4000 edges' dsts into a 60KB packed LDS histogram, dumps to partA[b][w].
__global__ __launch_bounds__(256) void k_init(int* __restrict__ ovfc,
                                              int* __restrict__ esrc2,
                                              const float* __restrict__ W1,
                                              __half* __restrict__ Wt1,
                                              const float* __restrict__ W2,
                                              __half* __restrict__ Wt2,
                                              const int* __restrict__ edge,
                                              unsigned* __restrict__ partA) {
    __shared__ unsigned bins[NW]; // 60000 B
    if (blockIdx.x < INIT_BLOCKS) {
        int t = blockIdx.x * 256 + threadIdx.x;
        int nthr = INIT_BLOCKS * 256;
        for (int i = t; i < N_NODES; i += nthr) esrc2[i * BCAP] = i; // self-loop = slot 0
        if (t == 0) *ovfc = 0;
        const int T1 = IN_CH * D1, T2 = D1 * OUT_CH;
        for (int idx = t; idx < T1 + T2; idx += nthr) {
            if (idx < T1) {
                int k = idx / D1, n = idx - k * D1;
                Wt1[(size_t)n * IN_CH + k] = __float2half(W1[idx]);
            } else {
                int i2 = idx - T1;
                int k = i2 / OUT_CH, n = i2 - k * OUT_CH;
                Wt2[(size_t)n * D1 + k] = __float2half(W2[i2]);
            }
        }
    } else {
        int b = blockIdx.x - INIT_BLOCKS; // 0..119
        for (int i = threadIdx.x; i < NW; i += 256) bins[i] = 0;
        __syncthreads();
        int e0 = b * EPB;
        for (int e = e0 + ((int)threadIdx.x << 2); e < e0 + EPB; e += 1024) {
            int4 dd = *(const int4*)(edge + N_EDGES + e);
            atomicAdd(&bins[dd.x >> 1], (dd.x & 1) ? 65536u : 1u);
            atomicAdd(&bins[dd.y >> 1], (dd.y & 1) ? 65536u : 1u);
            atomicAdd(&bins[dd.z >> 1], (dd.z & 1) ? 65536u : 1u);
            atomicAdd(&bins[dd.w >> 1], (dd.w & 1) ? 65536u : 1u);
        }
        __syncthreads();
        for (int i = threadIdx.x; i < NW; i += 256)
            partA[(size_t)b * NW + i] = bins[i];
    }
}

// ================ K1: layer-1 GEMM || prefix over block-partials ================
// GEMM branch FIRST (116-VGPR ordering, R15/R16-proven). Prefix: thread per
// node-pair w: exclusive prefix of partA[.][w] over the 120 blocks -> offA
// (u16 pair, clamped at 64), dense cnt[n] = 1 + deg (exact u32).
__global__ __launch_bounds__(256) void k_build_gemm1(const unsigned* __restrict__ partA,
                                                     unsigned* __restrict__ offA,
                                                     int* __restrict__ cnt,
                                                     const float* __restrict__ x,
                                                     const __half* __restrict__ Wt1,
                                                     __half* __restrict__ h1,
                                                     const float* __restrict__ att_src1,
                                                     const float* __restrict__ att_dst1,
                                                     float* __restrict__ as1,
                                                     float* __restrict__ ad1) {
    int lane = threadIdx.x & 63, wv = threadIdx.x >> 6;
    if (blockIdx.x < GEMM1_BLOCKS) {
        gemm_phase<HEADS1, 8, float>(x, Wt1, h1, IN_CH, att_src1, att_dst1, as1, ad1,
                                     blockIdx.x * 4 + wv, GEMM1_BLOCKS * 4, lane);
    } else {
        int w = (blockIdx.x - GEMM1_BLOCKS) * 256 + threadIdx.x;
        if (w < NW) {
            unsigned s0 = 1, s1 = 1; // slot 0 = self-loop
            for (int b = 0; b < BB; ++b) {
                unsigned v = partA[(size_t)b * NW + w];
                offA[(size_t)b * NW + w] = min(s0, 64u) | (min(s1, 64u) << 16);
                s0 += v & 0xFFFFu;
                s1 += v >> 16;
            }
            cnt[2 * w] = (int)s0;
            cnt[2 * w + 1] = (int)s1;
        }
    }
}

// ================ K1.5: pass B — rank + scatter (all lanes active, no filtering) ================
__global__ __launch_bounds__(256) void k_rank(const int* __restrict__ edge,
                                              const unsigned* __restrict__ offA,
                                              int* __restrict__ esrc2,
                                              int* __restrict__ ovf_cnt,
                                              int* __restrict__ ovf) {
    __shared__ unsigned bins[NW];
    int b = blockIdx.x;
    for (int i = threadIdx.x; i < NW; i += 256) bins[i] = 0;
    __syncthreads();
    int e0 = b * EPB;
    for (int e = e0 + ((int)threadIdx.x << 2); e < e0 + EPB; e += 1024) {
        int4 dd = *(const int4*)(edge + N_EDGES + e);
        int4 ss = *(const int4*)(edge + e);
        int dv[4] = {dd.x, dd.y, dd.z, dd.w};
        int sv[4] = {ss.x, ss.y, ss.z, ss.w};
#pragma unroll
        for (int u = 0; u < 4; ++u) {
            int d = dv[u];
            unsigned ret = atomicAdd(&bins[d >> 1], (d & 1) ? 65536u : 1u);
            unsigned lr = (d & 1) ? (ret >> 16) : (ret & 0xFFFFu);
            unsigned off = offA[(size_t)b * NW + (d >> 1)];
            off = (d & 1) ? (off >> 16) : (off & 0xFFFFu);
            unsigned slot = off + lr;
            if (slot < BCAP) {
                esrc2[(d << 6) + slot] = sv[u];
            } else { // true global rank >= 64 (off clamped at 64 keeps this exact)
                int oi = atomicAdd(ovf_cnt, 1);
                if (oi < OVF_CAP) { ovf[2 * oi] = d; ovf[2 * oi + 1] = sv[u]; }
            }
        }
    }
}

// ================ head-merged softmax + aggregate — ONE WAVE PER NODE (R21-proven) ================
// Contiguous slots 0..deg-1 (deg = cnt[n] incl. self-loop). One esrc2 gather,
// scores fetched for all heads at once (node-major [j][SP]); NH independent
// shuffle-reduce trees pipelined. Gather: lane = es*8+cg, 4 independent 16B
// loads, __hfma2, LDS pad-9 transpose reduce.
template<int NH, bool RELU>
__global__ __launch_bounds__(256) void k_attn_agg(const int* __restrict__ cnt,
                                                  const int* __restrict__ esrc2,
                                                  const int* __restrict__ ovf_cnt,
                                                  const int* __restrict__ ovf,
                                                  const __half* __restrict__ hf,   // [N][NH*64]
                                                  const float* __restrict__ a_src, // [N][SP]
                                                  const float* __restrict__ a_dst, // [N][SP]
                                                  const float* __restrict__ bias,  // [NH*64]
                                                  __half* __restrict__ zout) {     // [N][NH*64]
    const int SP = (NH == 1) ? 1 : 8;
    __shared__ unsigned wpk[4][NH][64];
    __shared__ int jbuf[4][64];
    __shared__ float red[4][584];
    int node = (blockIdx.x * 256 + threadIdx.x) >> 6;
    int lane = threadIdx.x & 63;
    int wv = threadIdx.x >> 6;
    if (node >= N_NODES) return;
    int deg = cnt[node];
    const int RS = NH * 64;
    // dst-scores for this node (wave-uniform broadcast loads)
    float da[NH];
    if constexpr (NH == 1) {
        da[0] = a_dst[node];
    } else {
        float4 d0 = *(const float4*)(a_dst + (size_t)node * SP);
        da[0] = d0.x; da[1] = d0.y; da[2] = d0.z; da[3] = d0.w;
        da[4] = a_dst[(size_t)node * SP + 4];
    }
    if (deg <= BCAP) {
        int es = lane >> 3, cg = lane & 7;
        int joff = 0;
        float e[NH];
#pragma unroll
        for (int h = 0; h < NH; ++h) e[h] = 0.f;
        if (lane < deg) {
            int j = esrc2[node * BCAP + lane];
            joff = j * RS;
            if constexpr (NH == 1) {
                e[0] = __expf(leaky(a_src[j] + da[0]));
            } else {
                float4 s0 = *(const float4*)(a_src + (size_t)j * SP);
                float s4 = a_src[(size_t)j * SP + 4];
                e[0] = __expf(leaky(s0.x + da[0]));
                e[1] = __expf(leaky(s0.y + da[1]));
                e[2] = __expf(leaky(s0.z + da[2]));
                e[3] = __expf(leaky(s0.w + da[3]));
                e[4] = __expf(leaky(s4 + da[4]));
            }
        }
        float s[NH];
#pragma unroll
        for (int h = 0; h < NH; ++h) s[h] = e[h];
#pragma unroll
        for (int off = 1; off < 64; off <<= 1) {
#pragma unroll
            for (int h = 0; h < NH; ++h) s[h] += __shfl_xor(s[h], off, 64);
        }
#pragma unroll
        for (int h = 0; h < NH; ++h) {
            float r = 1.f / (s[h] + 1e-16f);
            __half2 wn = __float2half2_rn(e[h] * r);
            wpk[wv][h][lane] = *(unsigned*)&wn;
        }
        jbuf[wv][lane] = joff;
#pragma unroll
        for (int h = 0; h < NH; ++h) {
            const __half* hbase = hf + h * 64 + cg * 8;
            __half2 acch[4] = {__half2{0, 0}, __half2{0, 0}, __half2{0, 0}, __half2{0, 0}};
            for (int k0 = 0; k0 < deg; k0 += 32) {
                int kA = k0 + es, kB = kA + 8, kC = kA + 16, kD = kA + 24;
                unsigned uA = wpk[wv][h][kA];
                unsigned uB = wpk[wv][h][kB];
                unsigned uC = wpk[wv][h][kC];
                unsigned uD = wpk[wv][h][kD];
                int jA = jbuf[wv][kA];
                int jB = jbuf[wv][kB];
                int jC = jbuf[wv][kC];
                int jD = jbuf[wv][kD];
                float4 vA = *(const float4*)(hbase + jA);
                float4 vB = *(const float4*)(hbase + jB);
                float4 vC = *(const float4*)(hbase + jC);
                float4 vD = *(const float4*)(hbase + jD);
                __half2 hwA = *(__half2*)&uA, hwB = *(__half2*)&uB;
                __half2 hwC = *(__half2*)&uC, hwD = *(__half2*)&uD;
                const __half2* pA = (const __half2*)&vA;
                const __half2* pB = (const __half2*)&vB;
                const __half2* pC = (const __half2*)&vC;
                const __half2* pD = (const __half2*)&vD;
#pragma unroll
                for (int i = 0; i < 4; ++i) {
                    acch[i] = __hfma2(pA[i], hwA, acch[i]);
                    acch[i] = __hfma2(pB[i], hwB, acch[i]);
                    acch[i] = __hfma2(pC[i], hwC, acch[i]);
                    acch[i] = __hfma2(pD[i], hwD, acch[i]);
                }
            }
            // fp32 cross-es reduce via LDS pad-9 transpose (2-way conflicts = free)
#pragma unroll
            for (int i = 0; i < 4; ++i) {
                float2 f = __half22float2(acch[i]);
                red[wv][(cg * 8 + 2 * i) * 9 + es] = f.x;
                red[wv][(cg * 8 + 2 * i + 1) * 9 + es] = f.y;
            }
            float tot = 0.f;
#pragma unroll
            for (int e2 = 0; e2 < 8; ++e2)
                tot += red[wv][lane * 9 + e2];
            float o = tot + bias[h * 64 + lane];
            if (RELU) o = fmaxf(o, 0.f);
            zout[(size_t)node * RS + h * 64 + lane] = __float2half(o);
        }
    } else {
        // cold path: deg > BCAP. lane = channel; bucket (64 full) + overflow scan.
        int ovn = min(*ovf_cnt, OVF_CAP);
#pragma unroll
        for (int h = 0; h < NH; ++h) {
            float adsth = da[h];
            float sden = __expf(leaky(a_src[(size_t)esrc2[node * BCAP + lane] * SP + h] + adsth));
#pragma unroll
            for (int off = 1; off < 64; off <<= 1)
                sden += __shfl_xor(sden, off, 64);
            float s2 = 0.f;
            for (int k = lane; k < ovn; k += 64)
                if (ovf[2 * k] == node)
                    s2 += __expf(leaky(a_src[(size_t)ovf[2 * k + 1] * SP + h] + adsth));
#pragma unroll
            for (int off = 1; off < 64; off <<= 1)
                s2 += __shfl_xor(s2, off, 64);
            float r = 1.f / (sden + s2 + 1e-16f);
            float a = 0.f;
            for (int k = 0; k < BCAP; ++k) {
                int j = esrc2[node * BCAP + k];
                float w = __expf(leaky(a_src[(size_t)j * SP + h] + adsth));
                a += w * __half2float(hf[(size_t)j * RS + h * 64 + lane]);
            }
            for (int k = 0; k < ovn; ++k) {
                if (ovf[2 * k] == node) {
                    int j = ovf[2 * k + 1];
                    float w = __expf(leaky(a_src[(size_t)j * SP + h] + adsth));
                    a += w * __half2float(hf[(size_t)j * RS + h * 64 + lane]);
                }
            }
            float o = a * r + bias[h * 64 + lane];
            if (RELU) o = fmaxf(o, 0.f);
            zout[(size_t)node * RS + h * 64 + lane] = __float2half(o);
        }
    }
}

// ================ layer-2 GEMM (slot-strided, 256-thr blocks) ================
__global__ __launch_bounds__(256) void k_gemm2(const __half* __restrict__ z1,
                                               const __half* __restrict__ Wt2,
                                               __half* __restrict__ h2,
                                               const float* __restrict__ att_src2,
                                               const float* __restrict__ att_dst2,
                                               float* __restrict__ as2,
                                               float* __restrict__ ad2) {
    int lane = threadIdx.x & 63, wv = threadIdx.x >> 6;
    gemm_phase<1, 1, __half>(z1, Wt2, h2, D1, att_src2, att_dst2, as2, ad2,
                             blockIdx.x * 4 + wv, gridDim.x * 4, lane);
}

// ================ decode: 8 lanes per edge, 16B fp16 loads, fdot2 ================
__global__ __launch_bounds__(256) void k_decode(const int* __restrict__ pos,
                                                const int* __restrict__ neg,
                                                const __half* __restrict__ z2,
                                                float* __restrict__ out) {
    int t = blockIdx.x * 256 + threadIdx.x;
    int e = t >> 3;
    int lc = t & 7;
    if (e >= 2 * PE_CNT) return;
    int a, b;
    if (e < PE_CNT) { a = pos[e]; b = pos[PE_CNT + e]; }
    else { int k = e - PE_CNT; a = neg[k]; b = neg[PE_CNT + k]; }
    union U { float4 f; f16x2 h[4]; __half2 hh[4]; } ua, ub;
    ua.f = *(const float4*)(z2 + (size_t)a * OUT_CH + lc * 8);
    ub.f = *(const float4*)(z2 + (size_t)b * OUT_CH + lc * 8);
    float v = 0.f;
#pragma unroll
    for (int i = 0; i < 4; ++i) {
#ifdef HAS_FDOT2
        v = __builtin_amdgcn_fdot2(ua.h[i], ub.h[i], v, false);
#else
        float2 fa = __half22float2(ua.hh[i]);
        float2 fb = __half22float2(ub.hh[i]);
        v += fa.x * fb.x + fa.y * fb.y;
#endif
    }
#pragma unroll
    for (int off = 1; off < 8; off <<= 1)
        v += __shfl_xor(v, off, 64);
    if (lc == 0) out[e] = v;
}

extern "C" void kernel_launch(void* const* d_in, const int* in_sizes, int n_in,
                              void* d_out, int out_size, void* d_ws, size_t ws_size,
                              hipStream_t stream) {
    const float* x        = (const float*)d_in[0];
    const int* edge_index = (const int*)d_in[1];
    const int* pos_ei     = (const int*)d_in[2];
    const int* neg_ei     = (const int*)d_in[3];
    const float* W1       = (const float*)d_in[4];
    const float* att_src1 = (const float*)d_in[5];
    const float* att_dst1 = (const float*)d_in[6];
    const float* b1       = (const float*)d_in[7];
    const float* W2       = (const float*)d_in[8];
    const float* att_src2 = (const float*)d_in[9];
    const float* att_dst2 = (const float*)d_in[10];
    const float* b2       = (const float*)d_in[11];
    float* out            = (float*)d_out;

    char* ws = (char*)d_ws;
    size_t off = 0;
    auto alloc = [&](size_t bytes) -> void* {
        void* p = ws + off;
        off = (off + bytes + 255) & ~(size_t)255;
        return p;
    };
    int* cnt     = (int*)alloc(sizeof(int) * N_NODES);
    int* ovfc    = (int*)alloc(sizeof(int) * 8);
    int* esrc2   = (int*)alloc(sizeof(int) * (size_t)N_NODES * BCAP);
    int* ovf     = (int*)alloc(sizeof(int) * (size_t)2 * OVF_CAP); // 512KB capped
    __half* h1   = (__half*)alloc(sizeof(__half) * (size_t)N_NODES * D1);
    __half* z1   = (__half*)alloc(sizeof(__half) * (size_t)N_NODES * D1);
    __half* h2   = (__half*)alloc(sizeof(__half) * (size_t)N_NODES * OUT_CH);
    __half* z2   = (__half*)alloc(sizeof(__half) * (size_t)N_NODES * OUT_CH);
    __half* Wt1  = (__half*)alloc(sizeof(__half) * (size_t)D1 * IN_CH);
    __half* Wt2  = (__half*)alloc(sizeof(__half) * (size_t)OUT_CH * D1);
    float* as1   = (float*)alloc(sizeof(float) * (size_t)N_NODES * 8); // [N][8] node-major, 5 used
    float* ad1   = (float*)alloc(sizeof(float) * (size_t)N_NODES * 8); // [N][8]
    float* as2   = (float*)alloc(sizeof(float) * (size_t)N_NODES);
    float* ad2   = (float*)alloc(sizeof(float) * (size_t)N_NODES);
    // partA/offA (7.2MB each) ALIAS z1's 19.2MB: both are dead after k_rank,
    // and z1 is first written in K2 which stream-orders after k_rank. 256-aligned
    // (7,200,000 % 256 == 0). This keeps total ws at ~56.7MB (R24's separate
    // allocations hit 74.6MB and crashed the ~64MB workspace).
    unsigned* partA = (unsigned*)z1;
    unsigned* offA  = (unsigned*)((char*)z1 + (size_t)BB * NW * sizeof(unsigned));

    // K0: init (self-loops, ovfc, weight prep) || pass A (LDS histogram -> partA)
    k_init<<<INIT_BLOCKS + BB, 256, 0, stream>>>(ovfc, esrc2, W1, Wt1, W2, Wt2,
                                                 edge_index, partA);
    // K1: layer-1 MFMA GEMM + scores || prefix (partA -> offA, cnt)
    k_build_gemm1<<<GEMM1_BLOCKS + PFX_BLOCKS, 256, 0, stream>>>(
        partA, offA, cnt, x, Wt1, h1, att_src1, att_dst1, as1, ad1);
    // K1.5: pass B — rank assignment + esrc2 scatter
    k_rank<<<BB, 256, 0, stream>>>(edge_index, offA, esrc2, ovfc, ovf);
    // K2: layer-1 softmax-aggregate (+relu) — one wave per node, 5 heads merged
    k_attn_agg<HEADS1, true><<<(N_NODES + 3) / 4, 256, 0, stream>>>(
        cnt, esrc2, ovfc, ovf, h1, as1, ad1, b1, z1);
    // K3: layer-2 GEMM + scores
    k_gemm2<<<469, 256, 0, stream>>>(z1, Wt2, h2, att_src2, att_dst2, as2, ad2);
    // K4: layer-2 softmax-aggregate
    k_attn_agg<1, false><<<(N_NODES + 3) / 4, 256, 0, stream>>>(
        cnt, esrc2, ovfc, ovf, h2, as2, ad2, b2, z2);
    // K5: decode
    k_decode<<<(2 * PE_CNT * 8 + 255) / 256, 256, 0, stream>>>(pos_ei, neg_ei, z2, out);

    (void)in_sizes; (void)n_in; (void)out_size; (void)ws_size;
}

// Round 7
// 206.792 us; speedup vs baseline: 2.2557x; 1.0032x over previous
//
#include <hip/hip_runtime.h>
#include <hip/hip_fp16.h>
#include <cstdint>
#include <cstddef>
#include <type_traits>

#define N_NODES 30000
#define N_EDGES 480000
#define N_EDGES_SL (N_EDGES + N_NODES) // 510000
#define IN_CH 128
#define HEADS1 5
#define C1 64
#define D1 (HEADS1 * C1) // 320
#define OUT_CH 64
#define PE_CNT 100000
#define NEG_SLOPE 0.2f
#define BCAP 64   // bucket: slot 0 = self-loop, slots 1..deg = edges (exact global ranks)
#define GEMM1_BLOCKS 469
#define INIT_BLOCKS 120     // 512-thr init blocks
#define BB 120              // builder blocks (pass A / pass B), 512 thr each
#define EPB (N_EDGES / BB)  // 4000 edges per builder block (exact)
#define NW (N_NODES / 2)    // 15000 packed u32 words (2 x u16 bins per word)
#define PFX_BLOCKS 59       // prefix blocks: 59*256 = 15104 >= NW
#define OVF_CAP 65536       // overflow list capacity (writes clamped; p(use)~1e-18)
// R26 = R25 (two-pass counting-sort CSR build, PASSED 207us) + three latency fixes:
//  (a) prefix: 120 SERIAL 60KB-strided dependent loads/thread (~600cy each ~ 30-45us,
//      K1's likely critical path) -> 10-wide independent load batches = 12 rounds.
//  (b) k_rank + K0-hist: 256 -> 512 threads/block (same 120 blocks, 60KB LDS):
//      serial scan length halves, wave count doubles.
//  (c) K2/K4 gather: deg is wave-uniform, avg 17; 47% of nodes have deg<=16 but
//      always paid the 4-chunk (32-slot) path -> add uniform-branch 2-chunk path.
// K2 analysis (R25 counters): FETCH 148.8MB = 8 XCDs x h1(19.2MB) = L2-compulsory
// floor for head-merged gather; 3.4TB/s, VALUBusy 50% -> jointly BW/VALU bound.
// Build-scheme invariants (R19-R21: global returning atomicAdd capped ~8/ns):
// each edge visited exactly twice, one block each, zero global returning atomics.

typedef _Float16 f16x8 __attribute__((ext_vector_type(8)));
typedef _Float16 f16x2 __attribute__((ext_vector_type(2)));
typedef float fx4 __attribute__((ext_vector_type(4)));

#if defined(__has_builtin)
#if __has_builtin(__builtin_amdgcn_fdot2)
#define HAS_FDOT2 1
#endif
#endif

static __device__ __forceinline__ float leaky(float x) {
    return fmaxf(x, NEG_SLOPE * x); // valid for 0<slope<1
}

// ---------------- barrier-free MFMA fp16 GEMM phase + fused attention scores ----------------
// Wave-slot per 16-row tile (30000 = 16*1875). No LDS, no barriers.
// mfma_f32_16x16x32_f16 layouts (HW-verified): A: lane holds A[m=lane&15][k=quad*8+j];
// B: lane holds B[k=quad*8+j][n=lane&15] (contiguous in Wt[n][k]); D: D[row=quad*4+reg][col=lane&15].
// Scores written NODE-MAJOR with stride SP: as_out[row*SP + h].
template<int NH, int SP, typename AT>
static __device__ __forceinline__ void gemm_phase(const AT* __restrict__ A,
                                                  const __half* __restrict__ Wt,
                                                  __half* __restrict__ C, int K,
                                                  const float* __restrict__ att_src,
                                                  const float* __restrict__ att_dst,
                                                  float* __restrict__ as_out,
                                                  float* __restrict__ ad_out,
                                                  int slot, int nsl, int lane) {
    const int N = NH * 64;
    int q = lane >> 4, l16 = lane & 15;
    for (int tile = slot; tile < N_NODES / 16; tile += nsl) {
        int rowBase = tile * 16;
        int arow = rowBase + l16;
        fx4 zero4 = {0.f, 0.f, 0.f, 0.f};
        fx4 acc[NH][4];
#pragma unroll
        for (int h = 0; h < NH; ++h)
#pragma unroll
            for (int c = 0; c < 4; ++c) acc[h][c] = zero4;
        for (int kk = 0; kk < K; kk += 32) {
            f16x8 af;
            if constexpr (std::is_same<AT, float>::value) {
                const float4* s = (const float4*)(A + (size_t)arow * K + kk + q * 8);
                float4 v0 = s[0], v1 = s[1];
                af[0] = (_Float16)v0.x; af[1] = (_Float16)v0.y;
                af[2] = (_Float16)v0.z; af[3] = (_Float16)v0.w;
                af[4] = (_Float16)v1.x; af[5] = (_Float16)v1.y;
                af[6] = (_Float16)v1.z; af[7] = (_Float16)v1.w;
            } else {
                af = *(const f16x8*)((const __half*)A + (size_t)arow * K + kk + q * 8);
            }
#pragma unroll
            for (int h = 0; h < NH; ++h) {
#pragma unroll
                for (int c = 0; c < 4; ++c) {
                    int col = h * 64 + c * 16 + l16;
                    f16x8 bf = *(const f16x8*)(Wt + (size_t)col * K + kk + q * 8);
                    acc[h][c] = __builtin_amdgcn_mfma_f32_16x16x32_f16(af, bf, acc[h][c], 0, 0, 0);
                }
            }
        }
#pragma unroll
        for (int h = 0; h < NH; ++h) {
            float ps[4] = {0.f, 0.f, 0.f, 0.f};
            float pd[4] = {0.f, 0.f, 0.f, 0.f};
#pragma unroll
            for (int c = 0; c < 4; ++c) {
                int gcol = h * 64 + c * 16 + l16;
                float av = att_src[gcol];
                float dv = att_dst[gcol];
#pragma unroll
                for (int reg = 0; reg < 4; ++reg) {
                    int grow = rowBase + q * 4 + reg;
                    float val = acc[h][c][reg];
                    C[(size_t)grow * N + gcol] = __float2half(val);
                    ps[reg] += val * av;
                    pd[reg] += val * dv;
                }
            }
#pragma unroll
            for (int off = 1; off < 16; off <<= 1) {
#pragma unroll
                for (int reg = 0; reg < 4; ++reg) {
                    ps[reg] += __shfl_xor(ps[reg], off, 64);
                    pd[reg] += __shfl_xor(pd[reg], off, 64);
                }
            }
            if (l16 == 0) {
#pragma unroll
                for (int reg = 0; reg < 4; ++reg) {
                    int grow = rowBase + q * 4 + reg;
                    as_out[(size_t)grow * SP + h] = ps[reg];
                    ad_out[(size_t)grow * SP + h] = pd[reg];
                }
            }
        }
    }
}

// ================ K0 (512-thr): init (self-loops, ovfc, weight transpose) || pass A histogram ================
// Blocks [0,120): init. Blocks [120,240): builder block b histograms its 4000
// edges' dsts into a 60KB packed LDS histogram, dumps to partA[b][w].
__global__ __launch_bounds__(512) void k_init(int* __restrict__ ovfc,
                                              int* __restrict__ esrc2,
                                              const float* __restrict__ W1,
                                              __half* __restrict__ Wt1,
                                              const float* __restrict__ W2,
                                              __half* __restrict__ Wt2,
                                              const int* __restrict__ edge,
                                              unsigned* __restrict__ partA) {
    __shared__ unsigned bins[NW]; // 60000 B
    if (blockIdx.x < INIT_BLOCKS) {
        int t = blockIdx.x * 512 + threadIdx.x;
        int nthr = INIT_BLOCKS * 512; // 61440
        for (int i = t; i < N_NODES; i += nthr) esrc2[i * BCAP] = i; // self-loop = slot 0
        if (t == 0) *ovfc = 0;
        const int T1 = IN_CH * D1, T2 = D1 * OUT_CH; // 40960 + 20480 = 61440
        for (int idx = t; idx < T1 + T2; idx += nthr) {
            if (idx < T1) {
                int k = idx / D1, n = idx - k * D1;
                Wt1[(size_t)n * IN_CH + k] = __float2half(W1[idx]);
            } else {
                int i2 = idx - T1;
                int k = i2 / OUT_CH, n = i2 - k * OUT_CH;
                Wt2[(size_t)n * D1 + k] = __float2half(W2[i2]);
            }
        }
    } else {
        int b = blockIdx.x - INIT_BLOCKS; // 0..119
        for (int i = threadIdx.x; i < NW; i += 512) bins[i] = 0;
        __syncthreads();
        int e0 = b * EPB;
        for (int e = e0 + ((int)threadIdx.x << 2); e < e0 + EPB; e += 2048) {
            int4 dd = *(const int4*)(edge + N_EDGES + e);
            atomicAdd(&bins[dd.x >> 1], (dd.x & 1) ? 65536u : 1u);
            atomicAdd(&bins[dd.y >> 1], (dd.y & 1) ? 65536u : 1u);
            atomicAdd(&bins[dd.z >> 1], (dd.z & 1) ? 65536u : 1u);
            atomicAdd(&bins[dd.w >> 1], (dd.w & 1) ? 65536u : 1u);
        }
        __syncthreads();
        for (int i = threadIdx.x; i < NW; i += 512)
            partA[(size_t)b * NW + i] = bins[i];
    }
}

// ================ K1: layer-1 GEMM || prefix over block-partials (10-wide batched) ================
// GEMM branch FIRST (116-VGPR ordering, R15/R16-proven). Prefix: thread per
// node-pair w: exclusive prefix of partA[.][w] over 120 blocks. R26: loads are
// INDEPENDENT — batch 10 per round (12 latency rounds instead of 120 serial).
__global__ __launch_bounds__(256) void k_build_gemm1(const unsigned* __restrict__ partA,
                                                     unsigned* __restrict__ offA,
                                                     int* __restrict__ cnt,
                                                     const float* __restrict__ x,
                                                     const __half* __restrict__ Wt1,
                                                     __half* __restrict__ h1,
                                                     const float* __restrict__ att_src1,
                                                     const float* __restrict__ att_dst1,
                                                     float* __restrict__ as1,
                                                     float* __restrict__ ad1) {
    int lane = threadIdx.x & 63, wv = threadIdx.x >> 6;
    if (blockIdx.x < GEMM1_BLOCKS) {
        gemm_phase<HEADS1, 8, float>(x, Wt1, h1, IN_CH, att_src1, att_dst1, as1, ad1,
                                     blockIdx.x * 4 + wv, GEMM1_BLOCKS * 4, lane);
    } else {
        int w = (blockIdx.x - GEMM1_BLOCKS) * 256 + threadIdx.x;
        if (w < NW) {
            unsigned s0 = 1, s1 = 1; // slot 0 = self-loop
            for (int b0 = 0; b0 < BB; b0 += 10) {
                unsigned v[10];
#pragma unroll
                for (int u = 0; u < 10; ++u)
                    v[u] = partA[(size_t)(b0 + u) * NW + w];
#pragma unroll
                for (int u = 0; u < 10; ++u) {
                    offA[(size_t)(b0 + u) * NW + w] = min(s0, 64u) | (min(s1, 64u) << 16);
                    s0 += v[u] & 0xFFFFu;
                    s1 += v[u] >> 16;
                }
            }
            cnt[2 * w] = (int)s0;
            cnt[2 * w + 1] = (int)s1;
        }
    }
}

// ================ K1.5 (512-thr): pass B — rank + scatter (all lanes active) ================
__global__ __launch_bounds__(512) void k_rank(const int* __restrict__ edge,
                                              const unsigned* __restrict__ offA,
                                              int* __restrict__ esrc2,
                                              int* __restrict__ ovf_cnt,
                                              int* __restrict__ ovf) {
    __shared__ unsigned bins[NW];
    int b = blockIdx.x;
    for (int i = threadIdx.x; i < NW; i += 512) bins[i] = 0;
    __syncthreads();
    int e0 = b * EPB;
    for (int e = e0 + ((int)threadIdx.x << 2); e < e0 + EPB; e += 2048) {
        int4 dd = *(const int4*)(edge + N_EDGES + e);
        int4 ss = *(const int4*)(edge + e);
        int dv[4] = {dd.x, dd.y, dd.z, dd.w};
        int sv[4] = {ss.x, ss.y, ss.z, ss.w};
#pragma unroll
        for (int u = 0; u < 4; ++u) {
            int d = dv[u];
            unsigned ret = atomicAdd(&bins[d >> 1], (d & 1) ? 65536u : 1u);
            unsigned lr = (d & 1) ? (ret >> 16) : (ret & 0xFFFFu);
            unsigned off = offA[(size_t)b * NW + (d >> 1)];
            off = (d & 1) ? (off >> 16) : (off & 0xFFFFu);
            unsigned slot = off + lr;
            if (slot < BCAP) {
                esrc2[(d << 6) + slot] = sv[u];
            } else { // true global rank >= 64 (off clamped at 64 keeps this exact)
                int oi = atomicAdd(ovf_cnt, 1);
                if (oi < OVF_CAP) { ovf[2 * oi] = d; ovf[2 * oi + 1] = sv[u]; }
            }
        }
    }
}

// ================ head-merged softmax + aggregate — ONE WAVE PER NODE (R21-proven) ================
// R26: deg is wave-uniform; 47% of nodes have deg<=16 -> uniform-branch 2-chunk
// gather path (half the loads/hfma2/LDS of the 4-chunk path). Invalid slots
// carry weight 0 (identical math). Gather: lane = es*8+cg, independent 16B
// loads, __hfma2, LDS pad-9 transpose reduce.
template<int NH, bool RELU>
__global__ __launch_bounds__(256) void k_attn_agg(const int* __restrict__ cnt,
                                                  const int* __restrict__ esrc2,
                                                  const int* __restrict__ ovf_cnt,
                                                  const int* __restrict__ ovf,
                                                  const __half* __restrict__ hf,   // [N][NH*64]
                                                  const float* __restrict__ a_src, // [N][SP]
                                                  const float* __restrict__ a_dst, // [N][SP]
                                                  const float* __restrict__ bias,  // [NH*64]
                                                  __half* __restrict__ zout) {     // [N][NH*64]
    const int SP = (NH == 1) ? 1 : 8;
    __shared__ unsigned wpk[4][NH][64];
    __shared__ int jbuf[4][64];
    __shared__ float red[4][584];
    int node = (blockIdx.x * 256 + threadIdx.x) >> 6;
    int lane = threadIdx.x & 63;
    int wv = threadIdx.x >> 6;
    if (node >= N_NODES) return;
    int deg = cnt[node];
    const int RS = NH * 64;
    // dst-scores for this node (wave-uniform broadcast loads)
    float da[NH];
    if constexpr (NH == 1) {
        da[0] = a_dst[node];
    } else {
        float4 d0 = *(const float4*)(a_dst + (size_t)node * SP);
        da[0] = d0.x; da[1] = d0.y; da[2] = d0.z; da[3] = d0.w;
        da[4] = a_dst[(size_t)node * SP + 4];
    }
    if (deg <= BCAP) {
        int es = lane >> 3, cg = lane & 7;
        int joff = 0;
        float e[NH];
#pragma unroll
        for (int h = 0; h < NH; ++h) e[h] = 0.f;
        if (lane < deg) {
            int j = esrc2[node * BCAP + lane];
            joff = j * RS;
            if constexpr (NH == 1) {
                e[0] = __expf(leaky(a_src[j] + da[0]));
            } else {
                float4 s0 = *(const float4*)(a_src + (size_t)j * SP);
                float s4 = a_src[(size_t)j * SP + 4];
                e[0] = __expf(leaky(s0.x + da[0]));
                e[1] = __expf(leaky(s0.y + da[1]));
                e[2] = __expf(leaky(s0.z + da[2]));
                e[3] = __expf(leaky(s0.w + da[3]));
                e[4] = __expf(leaky(s4 + da[4]));
            }
        }
        float s[NH];
#pragma unroll
        for (int h = 0; h < NH; ++h) s[h] = e[h];
#pragma unroll
        for (int off = 1; off < 64; off <<= 1) {
#pragma unroll
            for (int h = 0; h < NH; ++h) s[h] += __shfl_xor(s[h], off, 64);
        }
#pragma unroll
        for (int h = 0; h < NH; ++h) {
            float r = 1.f / (s[h] + 1e-16f);
            __half2 wn = __float2half2_rn(e[h] * r);
            wpk[wv][h][lane] = *(unsigned*)&wn;
        }
        jbuf[wv][lane] = joff;
#pragma unroll
        for (int h = 0; h < NH; ++h) {
            const __half* hbase = hf + h * 64 + cg * 8;
            __half2 acch[4] = {__half2{0, 0}, __half2{0, 0}, __half2{0, 0}, __half2{0, 0}};
            if (deg <= 16) {
                // 2-chunk fast path: slots 0..15 only (47% of nodes)
                int kA = es, kB = es + 8;
                unsigned uA = wpk[wv][h][kA];
                unsigned uB = wpk[wv][h][kB];
                int jA = jbuf[wv][kA];
                int jB = jbuf[wv][kB];
                float4 vA = *(const float4*)(hbase + jA);
                float4 vB = *(const float4*)(hbase + jB);
                __half2 hwA = *(__half2*)&uA, hwB = *(__half2*)&uB;
                const __half2* pA = (const __half2*)&vA;
                const __half2* pB = (const __half2*)&vB;
#pragma unroll
                for (int i = 0; i < 4; ++i) {
                    acch[i] = __hfma2(pA[i], hwA, acch[i]);
                    acch[i] = __hfma2(pB[i], hwB, acch[i]);
                }
            } else {
                for (int k0 = 0; k0 < deg; k0 += 32) {
                    int kA = k0 + es, kB = kA + 8, kC = kA + 16, kD = kA + 24;
                    unsigned uA = wpk[wv][h][kA];
                    unsigned uB = wpk[wv][h][kB];
                    unsigned uC = wpk[wv][h][kC];
                    unsigned uD = wpk[wv][h][kD];
                    int jA = jbuf[wv][kA];
                    int jB = jbuf[wv][kB];
                    int jC = jbuf[wv][kC];
                    int jD = jbuf[wv][kD];
                    float4 vA = *(const float4*)(hbase + jA);
                    float4 vB = *(const float4*)(hbase + jB);
                    float4 vC = *(const float4*)(hbase + jC);
                    float4 vD = *(const float4*)(hbase + jD);
                    __half2 hwA = *(__half2*)&uA, hwB = *(__half2*)&uB;
                    __half2 hwC = *(__half2*)&uC, hwD = *(__half2*)&uD;
                    const __half2* pA = (const __half2*)&vA;
                    const __half2* pB = (const __half2*)&vB;
                    const __half2* pC = (const __half2*)&vC;
                    const __half2* pD = (const __half2*)&vD;
#pragma unroll
                    for (int i = 0; i < 4; ++i) {
                        acch[i] = __hfma2(pA[i], hwA, acch[i]);
                        acch[i] = __hfma2(pB[i], hwB, acch[i]);
                        acch[i] = __hfma2(pC[i], hwC, acch[i]);
                        acch[i] = __hfma2(pD[i], hwD, acch[i]);
                    }
                }
            }
            // fp32 cross-es reduce via LDS pad-9 transpose (2-way conflicts = free)
#pragma unroll
            for (int i = 0; i < 4; ++i) {
                float2 f = __half22float2(acch[i]);
                red[wv][(cg * 8 + 2 * i) * 9 + es] = f.x;
                red[wv][(cg * 8 + 2 * i + 1) * 9 + es] = f.y;
            }
            float tot = 0.f;
#pragma unroll
            for (int e2 = 0; e2 < 8; ++e2)
                tot += red[wv][lane * 9 + e2];
            float o = tot + bias[h * 64 + lane];
            if (RELU) o = fmaxf(o, 0.f);
            zout[(size_t)node * RS + h * 64 + lane] = __float2half(o);
        }
    } else {
        // cold path: deg > BCAP. lane = channel; bucket (64 full) + overflow scan.
        int ovn = min(*ovf_cnt, OVF_CAP);
#pragma unroll
        for (int h = 0; h < NH; ++h) {
            float adsth = da[h];
            float sden = __expf(leaky(a_src[(size_t)esrc2[node * BCAP + lane] * SP + h] + adsth));
#pragma unroll
            for (int off = 1; off < 64; off <<= 1)
                sden += __shfl_xor(sden, off, 64);
            float s2 = 0.f;
            for (int k = lane; k < ovn; k += 64)
                if (ovf[2 * k] == node)
                    s2 += __expf(leaky(a_src[(size_t)ovf[2 * k + 1] * SP + h] + adsth));
#pragma unroll
            for (int off = 1; off < 64; off <<= 1)
                s2 += __shfl_xor(s2, off, 64);
            float r = 1.f / (sden + s2 + 1e-16f);
            float a = 0.f;
            for (int k = 0; k < BCAP; ++k) {
                int j = esrc2[node * BCAP + k];
                float w = __expf(leaky(a_src[(size_t)j * SP + h] + adsth));
                a += w * __half2float(hf[(size_t)j * RS + h * 64 + lane]);
            }
            for (int k = 0; k < ovn; ++k) {
                if (ovf[2 * k] == node) {
                    int j = ovf[2 * k + 1];
                    float w = __expf(leaky(a_src[(size_t)j * SP + h] + adsth));
                    a += w * __half2float(hf[(size_t)j * RS + h * 64 + lane]);
                }
            }
            float o = a * r + bias[h * 64 + lane];
            if (RELU) o = fmaxf(o, 0.f);
            zout[(size_t)node * RS + h * 64 + lane] = __float2half(o);
        }
    }
}

// ================ layer-2 GEMM (slot-strided, 256-thr blocks) ================
__global__ __launch_bounds__(256) void k_gemm2(const __half* __restrict__ z1,
                                               const __half* __restrict__ Wt2,
                                               __half* __restrict__ h2,
                                               const float* __restrict__ att_src2,
                                               const float* __restrict__ att_dst2,
                                               float* __restrict__ as2,
                                               float* __restrict__ ad2) {
    int lane = threadIdx.x & 63, wv = threadIdx.x >> 6;
    gemm_phase<1, 1, __half>(z1, Wt2, h2, D1, att_src2, att_dst2, as2, ad2,
                             blockIdx.x * 4 + wv, gridDim.x * 4, lane);
}

// ================ decode: 8 lanes per edge, 16B fp16 loads, fdot2 ================
__global__ __launch_bounds__(256) void k_decode(const int* __restrict__ pos,
                                                const int* __restrict__ neg,
                                                const __half* __restrict__ z2,
                                                float* __restrict__ out) {
    int t = blockIdx.x * 256 + threadIdx.x;
    int e = t >> 3;
    int lc = t & 7;
    if (e >= 2 * PE_CNT) return;
    int a, b;
    if (e < PE_CNT) { a = pos[e]; b = pos[PE_CNT + e]; }
    else { int k = e - PE_CNT; a = neg[k]; b = neg[PE_CNT + k]; }
    union U { float4 f; f16x2 h[4]; __half2 hh[4]; } ua, ub;
    ua.f = *(const float4*)(z2 + (size_t)a * OUT_CH + lc * 8);
    ub.f = *(const float4*)(z2 + (size_t)b * OUT_CH + lc * 8);
    float v = 0.f;
#pragma unroll
    for (int i = 0; i < 4; ++i) {
#ifdef HAS_FDOT2
        v = __builtin_amdgcn_fdot2(ua.h[i], ub.h[i], v, false);
#else
        float2 fa = __half22float2(ua.hh[i]);
        float2 fb = __half22float2(ub.hh[i]);
        v += fa.x * fb.x + fa.y * fb.y;
#endif
    }
#pragma unroll
    for (int off = 1; off < 8; off <<= 1)
        v += __shfl_xor(v, off, 64);
    if (lc == 0) out[e] = v;
}

extern "C" void kernel_launch(void* const* d_in, const int* in_sizes, int n_in,
                              void* d_out, int out_size, void* d_ws, size_t ws_size,
                              hipStream_t stream) {
    const float* x        = (const float*)d_in[0];
    const int* edge_index = (const int*)d_in[1];
    const int* pos_ei     = (const int*)d_in[2];
    const int* neg_ei     = (const int*)d_in[3];
    const float* W1       = (const float*)d_in[4];
    const float* att_src1 = (const float*)d_in[5];
    const float* att_dst1 = (const float*)d_in[6];
    const float* b1       = (const float*)d_in[7];
    const float* W2       = (const float*)d_in[8];
    const float* att_src2 = (const float*)d_in[9];
    const float* att_dst2 = (const float*)d_in[10];
    const float* b2       = (const float*)d_in[11];
    float* out            = (float*)d_out;

    char* ws = (char*)d_ws;
    size_t off = 0;
    auto alloc = [&](size_t bytes) -> void* {
        void* p = ws + off;
        off = (off + bytes + 255) & ~(size_t)255;
        return p;
    };
    int* cnt     = (int*)alloc(sizeof(int) * N_NODES);
    int* ovfc    = (int*)alloc(sizeof(int) * 8);
    int* esrc2   = (int*)alloc(sizeof(int) * (size_t)N_NODES * BCAP);
    int* ovf     = (int*)alloc(sizeof(int) * (size_t)2 * OVF_CAP); // 512KB capped
    __half* h1   = (__half*)alloc(sizeof(__half) * (size_t)N_NODES * D1);
    __half* z1   = (__half*)alloc(sizeof(__half) * (size_t)N_NODES * D1);
    __half* h2   = (__half*)alloc(sizeof(__half) * (size_t)N_NODES * OUT_CH);
    __half* z2   = (__half*)alloc(sizeof(__half) * (size_t)N_NODES * OUT_CH);
    __half* Wt1  = (__half*)alloc(sizeof(__half) * (size_t)D1 * IN_CH);
    __half* Wt2  = (__half*)alloc(sizeof(__half) * (size_t)OUT_CH * D1);
    float* as1   = (float*)alloc(sizeof(float) * (size_t)N_NODES * 8); // [N][8] node-major, 5 used
    float* ad1   = (float*)alloc(sizeof(float) * (size_t)N_NODES * 8); // [N][8]
    float* as2   = (float*)alloc(sizeof(float) * (size_t)N_NODES);
    float* ad2   = (float*)alloc(sizeof(float) * (size_t)N_NODES);
    // partA/offA (7.2MB each) ALIAS z1's 19.2MB: both are dead after k_rank,
    // and z1 is first written in K2 which stream-orders after k_rank. 256-aligned
    // (7,200,000 % 256 == 0). Keeps total ws ~56.7MB (R24's separate allocations
    // hit 74.6MB and crashed the ~64MB workspace).
    unsigned* partA = (unsigned*)z1;
    unsigned* offA  = (unsigned*)((char*)z1 + (size_t)BB * NW * sizeof(unsigned));

    // K0: init (self-loops, ovfc, weight prep) || pass A (LDS histogram -> partA)
    k_init<<<INIT_BLOCKS + BB, 512, 0, stream>>>(ovfc, esrc2, W1, Wt1, W2, Wt2,
                                                 edge_index, partA);
    // K1: layer-1 MFMA GEMM + scores || prefix (partA -> offA, cnt)
    k_build_gemm1<<<GEMM1_BLOCKS + PFX_BLOCKS, 256, 0, stream>>>(
        partA, offA, cnt, x, Wt1, h1, att_src1, att_dst1, as1, ad1);
    // K1.5: pass B — rank assignment + esrc2 scatter
    k_rank<<<BB, 512, 0, stream>>>(edge_index, offA, esrc2, ovfc, ovf);
    // K2: layer-1 softmax-aggregate (+relu) — one wave per node, 5 heads merged
    k_attn_agg<HEADS1, true><<<(N_NODES + 3) / 4, 256, 0, stream>>>(
        cnt, esrc2, ovfc, ovf, h1, as1, ad1, b1, z1);
    // K3: layer-2 GEMM + scores
    k_gemm2<<<469, 256, 0, stream>>>(z1, Wt2, h2, att_src2, att_dst2, as2, ad2);
    // K4: layer-2 softmax-aggregate
    k_attn_agg<1, false><<<(N_NODES + 3) / 4, 256, 0, stream>>>(
        cnt, esrc2, ovfc, ovf, h2, as2, ad2, b2, z2);
    // K5: decode
    k_decode<<<(2 * PE_CNT * 8 + 255) / 256, 256, 0, stream>>>(pos_ei, neg_ei, z2, out);

    (void)in_sizes; (void)n_in; (void)out_size; (void)ws_size;
}

// Round 8
// 205.936 us; speedup vs baseline: 2.2650x; 1.0042x over previous
//
#include <hip/hip_runtime.h>
#include <hip/hip_fp16.h>
#include <cstdint>
#include <cstddef>
#include <type_traits>

#define N_NODES 30000
#define N_EDGES 480000
#define N_EDGES_SL (N_EDGES + N_NODES) // 510000
#define IN_CH 128
#define HEADS1 5
#define C1 64
#define D1 (HEADS1 * C1) // 320
#define OUT_CH 64
#define PE_CNT 100000
#define NEG_SLOPE 0.2f
#define BCAP 64   // bucket: slot 0 = self-loop, slots 1..deg = edges (exact global ranks)
#define GEMM1_BLOCKS 469
#define INIT_BLOCKS 120     // 512-thr init blocks
#define BB 120              // builder blocks (pass A / pass B), 512 thr each
#define EPB (N_EDGES / BB)  // 4000 edges per builder block (exact)
#define NW (N_NODES / 2)    // 15000 packed u32 words (2 x u16 bins per word)
#define PFX_BLOCKS 59       // prefix blocks: 59*256 = 15104 >= NW
#define OVF_CAP 65536       // overflow list capacity (writes clamped; p(use)~1e-18)
// R27 = R26 (206.8us) + K2/K4 head-loop software pipeline.
// R26 verdict: K2's deg<=16 VALU cut (VALUBusy 50->41.5%) left duration FLAT
// (49.6->48.9) -> K2 is memory-side bound. Request stream = 326MB/48.9us =
// 6.7TB/s, far under L2 aggregate; VALU 41%, occ 53% -> nothing saturated.
// Remaining theory: the 5 head-iterations are SERIAL (VGPR=40 — compiler kept
// no loads in flight across heads), each eating a full L3-hit latency with only
// ~35-150cy of cover -> ~5 exposed latencies/node. Fix: issue head h+1's gather
// loads BEFORE consuming head h + running its epilogue (epilogue becomes the
// latency cover). 3-way on wave-uniform deg: <=16 (2-slot), <=32 (4-slot, 97%
// of nodes), >32 (rare, old loop). Null result => K2 at request-BW floor, done.
// Build scheme (R25-proven): two-pass counting sort, each edge visited exactly
// twice, zero global returning atomics (R19-R21: that path caps ~8/ns = 60us).

typedef _Float16 f16x8 __attribute__((ext_vector_type(8)));
typedef _Float16 f16x2 __attribute__((ext_vector_type(2)));
typedef float fx4 __attribute__((ext_vector_type(4)));

#if defined(__has_builtin)
#if __has_builtin(__builtin_amdgcn_fdot2)
#define HAS_FDOT2 1
#endif
#endif

static __device__ __forceinline__ float leaky(float x) {
    return fmaxf(x, NEG_SLOPE * x); // valid for 0<slope<1
}

// ---------------- barrier-free MFMA fp16 GEMM phase + fused attention scores ----------------
// Wave-slot per 16-row tile (30000 = 16*1875). No LDS, no barriers.
// mfma_f32_16x16x32_f16 layouts (HW-verified): A: lane holds A[m=lane&15][k=quad*8+j];
// B: lane holds B[k=quad*8+j][n=lane&15] (contiguous in Wt[n][k]); D: D[row=quad*4+reg][col=lane&15].
// Scores written NODE-MAJOR with stride SP: as_out[row*SP + h].
template<int NH, int SP, typename AT>
static __device__ __forceinline__ void gemm_phase(const AT* __restrict__ A,
                                                  const __half* __restrict__ Wt,
                                                  __half* __restrict__ C, int K,
                                                  const float* __restrict__ att_src,
                                                  const float* __restrict__ att_dst,
                                                  float* __restrict__ as_out,
                                                  float* __restrict__ ad_out,
                                                  int slot, int nsl, int lane) {
    const int N = NH * 64;
    int q = lane >> 4, l16 = lane & 15;
    for (int tile = slot; tile < N_NODES / 16; tile += nsl) {
        int rowBase = tile * 16;
        int arow = rowBase + l16;
        fx4 zero4 = {0.f, 0.f, 0.f, 0.f};
        fx4 acc[NH][4];
#pragma unroll
        for (int h = 0; h < NH; ++h)
#pragma unroll
            for (int c = 0; c < 4; ++c) acc[h][c] = zero4;
        for (int kk = 0; kk < K; kk += 32) {
            f16x8 af;
            if constexpr (std::is_same<AT, float>::value) {
                const float4* s = (const float4*)(A + (size_t)arow * K + kk + q * 8);
                float4 v0 = s[0], v1 = s[1];
                af[0] = (_Float16)v0.x; af[1] = (_Float16)v0.y;
                af[2] = (_Float16)v0.z; af[3] = (_Float16)v0.w;
                af[4] = (_Float16)v1.x; af[5] = (_Float16)v1.y;
                af[6] = (_Float16)v1.z; af[7] = (_Float16)v1.w;
            } else {
                af = *(const f16x8*)((const __half*)A + (size_t)arow * K + kk + q * 8);
            }
#pragma unroll
            for (int h = 0; h < NH; ++h) {
#pragma unroll
                for (int c = 0; c < 4; ++c) {
                    int col = h * 64 + c * 16 + l16;
                    f16x8 bf = *(const f16x8*)(Wt + (size_t)col * K + kk + q * 8);
                    acc[h][c] = __builtin_amdgcn_mfma_f32_16x16x32_f16(af, bf, acc[h][c], 0, 0, 0);
                }
            }
        }
#pragma unroll
        for (int h = 0; h < NH; ++h) {
            float ps[4] = {0.f, 0.f, 0.f, 0.f};
            float pd[4] = {0.f, 0.f, 0.f, 0.f};
#pragma unroll
            for (int c = 0; c < 4; ++c) {
                int gcol = h * 64 + c * 16 + l16;
                float av = att_src[gcol];
                float dv = att_dst[gcol];
#pragma unroll
                for (int reg = 0; reg < 4; ++reg) {
                    int grow = rowBase + q * 4 + reg;
                    float val = acc[h][c][reg];
                    C[(size_t)grow * N + gcol] = __float2half(val);
                    ps[reg] += val * av;
                    pd[reg] += val * dv;
                }
            }
#pragma unroll
            for (int off = 1; off < 16; off <<= 1) {
#pragma unroll
                for (int reg = 0; reg < 4; ++reg) {
                    ps[reg] += __shfl_xor(ps[reg], off, 64);
                    pd[reg] += __shfl_xor(pd[reg], off, 64);
                }
            }
            if (l16 == 0) {
#pragma unroll
                for (int reg = 0; reg < 4; ++reg) {
                    int grow = rowBase + q * 4 + reg;
                    as_out[(size_t)grow * SP + h] = ps[reg];
                    ad_out[(size_t)grow * SP + h] = pd[reg];
                }
            }
        }
    }
}

// ================ K0 (512-thr): init (self-loops, ovfc, weight transpose) || pass A histogram ================
__global__ __launch_bounds__(512) void k_init(int* __restrict__ ovfc,
                                              int* __restrict__ esrc2,
                                              const float* __restrict__ W1,
                                              __half* __restrict__ Wt1,
                                              const float* __restrict__ W2,
                                              __half* __restrict__ Wt2,
                                              const int* __restrict__ edge,
                                              unsigned* __restrict__ partA) {
    __shared__ unsigned bins[NW]; // 60000 B
    if (blockIdx.x < INIT_BLOCKS) {
        int t = blockIdx.x * 512 + threadIdx.x;
        int nthr = INIT_BLOCKS * 512; // 61440
        for (int i = t; i < N_NODES; i += nthr) esrc2[i * BCAP] = i; // self-loop = slot 0
        if (t == 0) *ovfc = 0;
        const int T1 = IN_CH * D1, T2 = D1 * OUT_CH; // 40960 + 20480 = 61440
        for (int idx = t; idx < T1 + T2; idx += nthr) {
            if (idx < T1) {
                int k = idx / D1, n = idx - k * D1;
                Wt1[(size_t)n * IN_CH + k] = __float2half(W1[idx]);
            } else {
                int i2 = idx - T1;
                int k = i2 / OUT_CH, n = i2 - k * OUT_CH;
                Wt2[(size_t)n * D1 + k] = __float2half(W2[i2]);
            }
        }
    } else {
        int b = blockIdx.x - INIT_BLOCKS; // 0..119
        for (int i = threadIdx.x; i < NW; i += 512) bins[i] = 0;
        __syncthreads();
        int e0 = b * EPB;
        for (int e = e0 + ((int)threadIdx.x << 2); e < e0 + EPB; e += 2048) {
            int4 dd = *(const int4*)(edge + N_EDGES + e);
            atomicAdd(&bins[dd.x >> 1], (dd.x & 1) ? 65536u : 1u);
            atomicAdd(&bins[dd.y >> 1], (dd.y & 1) ? 65536u : 1u);
            atomicAdd(&bins[dd.z >> 1], (dd.z & 1) ? 65536u : 1u);
            atomicAdd(&bins[dd.w >> 1], (dd.w & 1) ? 65536u : 1u);
        }
        __syncthreads();
        for (int i = threadIdx.x; i < NW; i += 512)
            partA[(size_t)b * NW + i] = bins[i];
    }
}

// ================ K1: layer-1 GEMM || prefix over block-partials (10-wide batched) ================
__global__ __launch_bounds__(256) void k_build_gemm1(const unsigned* __restrict__ partA,
                                                     unsigned* __restrict__ offA,
                                                     int* __restrict__ cnt,
                                                     const float* __restrict__ x,
                                                     const __half* __restrict__ Wt1,
                                                     __half* __restrict__ h1,
                                                     const float* __restrict__ att_src1,
                                                     const float* __restrict__ att_dst1,
                                                     float* __restrict__ as1,
                                                     float* __restrict__ ad1) {
    int lane = threadIdx.x & 63, wv = threadIdx.x >> 6;
    if (blockIdx.x < GEMM1_BLOCKS) {
        gemm_phase<HEADS1, 8, float>(x, Wt1, h1, IN_CH, att_src1, att_dst1, as1, ad1,
                                     blockIdx.x * 4 + wv, GEMM1_BLOCKS * 4, lane);
    } else {
        int w = (blockIdx.x - GEMM1_BLOCKS) * 256 + threadIdx.x;
        if (w < NW) {
            unsigned s0 = 1, s1 = 1; // slot 0 = self-loop
            for (int b0 = 0; b0 < BB; b0 += 10) {
                unsigned v[10];
#pragma unroll
                for (int u = 0; u < 10; ++u)
                    v[u] = partA[(size_t)(b0 + u) * NW + w];
#pragma unroll
                for (int u = 0; u < 10; ++u) {
                    offA[(size_t)(b0 + u) * NW + w] = min(s0, 64u) | (min(s1, 64u) << 16);
                    s0 += v[u] & 0xFFFFu;
                    s1 += v[u] >> 16;
                }
            }
            cnt[2 * w] = (int)s0;
            cnt[2 * w + 1] = (int)s1;
        }
    }
}

// ================ K1.5 (512-thr): pass B — rank + scatter (all lanes active) ================
__global__ __launch_bounds__(512) void k_rank(const int* __restrict__ edge,
                                              const unsigned* __restrict__ offA,
                                              int* __restrict__ esrc2,
                                              int* __restrict__ ovf_cnt,
                                              int* __restrict__ ovf) {
    __shared__ unsigned bins[NW];
    int b = blockIdx.x;
    for (int i = threadIdx.x; i < NW; i += 512) bins[i] = 0;
    __syncthreads();
    int e0 = b * EPB;
    for (int e = e0 + ((int)threadIdx.x << 2); e < e0 + EPB; e += 2048) {
        int4 dd = *(const int4*)(edge + N_EDGES + e);
        int4 ss = *(const int4*)(edge + e);
        int dv[4] = {dd.x, dd.y, dd.z, dd.w};
        int sv[4] = {ss.x, ss.y, ss.z, ss.w};
#pragma unroll
        for (int u = 0; u < 4; ++u) {
            int d = dv[u];
            unsigned ret = atomicAdd(&bins[d >> 1], (d & 1) ? 65536u : 1u);
            unsigned lr = (d & 1) ? (ret >> 16) : (ret & 0xFFFFu);
            unsigned off = offA[(size_t)b * NW + (d >> 1)];
            off = (d & 1) ? (off >> 16) : (off & 0xFFFFu);
            unsigned slot = off + lr;
            if (slot < BCAP) {
                esrc2[(d << 6) + slot] = sv[u];
            } else { // true global rank >= 64 (off clamped at 64 keeps this exact)
                int oi = atomicAdd(ovf_cnt, 1);
                if (oi < OVF_CAP) { ovf[2 * oi] = d; ovf[2 * oi + 1] = sv[u]; }
            }
        }
    }
}

// ---------------- R27: pipelined gather — issue head h+1's loads before consuming head h ----------------
// NS = slots covered (2 for deg<=16, 4 for deg<=32). Epilogue (LDS pad-9 transpose +
// reduce + store) runs while next head's loads are in flight -> 1 exposed latency
// per node instead of NH. Invalid slots carry weight 0 (identical math).
template<int NH, int NS, bool RELU>
static __device__ __forceinline__ void gather_pipe(const __half* __restrict__ base, // hf + cg*8
                                                   const unsigned (&wpkw)[NH][64],
                                                   const int (&jbufw)[64],
                                                   float (&redw)[584],
                                                   const float* __restrict__ bias,
                                                   __half* __restrict__ zrow, // zout + node*RS
                                                   int es, int cg, int lane) {
    int kA = es, kB = es + 8;
    int kC = es + 16, kD = es + 24;
    int jA = jbufw[kA], jB = jbufw[kB];
    int jC = (NS == 4) ? jbufw[kC] : 0, jD = (NS == 4) ? jbufw[kD] : 0;
    float4 vA = *(const float4*)(base + jA);
    float4 vB = *(const float4*)(base + jB);
    float4 vC, vD;
    if (NS == 4) {
        vC = *(const float4*)(base + jC);
        vD = *(const float4*)(base + jD);
    }
#pragma unroll
    for (int h = 0; h < NH; ++h) {
        float4 nA, nB, nC, nD;
        if (h + 1 < NH) { // issue next head's loads FIRST (the pipeline)
            const __half* nb = base + (h + 1) * 64;
            nA = *(const float4*)(nb + jA);
            nB = *(const float4*)(nb + jB);
            if (NS == 4) {
                nC = *(const float4*)(nb + jC);
                nD = *(const float4*)(nb + jD);
            }
        }
        unsigned uA = wpkw[h][kA], uB = wpkw[h][kB];
        __half2 hwA = *(__half2*)&uA, hwB = *(__half2*)&uB;
        const __half2* pA = (const __half2*)&vA;
        const __half2* pB = (const __half2*)&vB;
        __half2 a2[4] = {__half2{0, 0}, __half2{0, 0}, __half2{0, 0}, __half2{0, 0}};
#pragma unroll
        for (int i = 0; i < 4; ++i) {
            a2[i] = __hfma2(pA[i], hwA, a2[i]);
            a2[i] = __hfma2(pB[i], hwB, a2[i]);
        }
        if (NS == 4) {
            unsigned uC = wpkw[h][kC], uD = wpkw[h][kD];
            __half2 hwC = *(__half2*)&uC, hwD = *(__half2*)&uD;
            const __half2* pC = (const __half2*)&vC;
            const __half2* pD = (const __half2*)&vD;
#pragma unroll
            for (int i = 0; i < 4; ++i) {
                a2[i] = __hfma2(pC[i], hwC, a2[i]);
                a2[i] = __hfma2(pD[i], hwD, a2[i]);
            }
        }
        // epilogue for head h (covers next head's load latency)
#pragma unroll
        for (int i = 0; i < 4; ++i) {
            float2 f = __half22float2(a2[i]);
            redw[(cg * 8 + 2 * i) * 9 + es] = f.x;
            redw[(cg * 8 + 2 * i + 1) * 9 + es] = f.y;
        }
        float tot = 0.f;
#pragma unroll
        for (int e2 = 0; e2 < 8; ++e2)
            tot += redw[lane * 9 + e2];
        float o = tot + bias[h * 64 + lane];
        if (RELU) o = fmaxf(o, 0.f);
        zrow[h * 64 + lane] = __float2half(o);
        vA = nA; vB = nB;
        if (NS == 4) { vC = nC; vD = nD; }
    }
}

// ================ head-merged softmax + aggregate — ONE WAVE PER NODE ================
// Prologue (R21-proven): one esrc2 gather, all heads' scores via one float4 + scalar
// (node-major [j][SP]), NH pipelined shuffle-reduce trees, weights packed in LDS.
// Gather (R27): deg-uniform 3-way -> pipelined 2-slot (deg<=16) / 4-slot (deg<=32) /
// legacy serial loop (deg>32, ~0.04% of nodes).
template<int NH, bool RELU>
__global__ __launch_bounds__(256) void k_attn_agg(const int* __restrict__ cnt,
                                                  const int* __restrict__ esrc2,
                                                  const int* __restrict__ ovf_cnt,
                                                  const int* __restrict__ ovf,
                                                  const __half* __restrict__ hf,   // [N][NH*64]
                                                  const float* __restrict__ a_src, // [N][SP]
                                                  const float* __restrict__ a_dst, // [N][SP]
                                                  const float* __restrict__ bias,  // [NH*64]
                                                  __half* __restrict__ zout) {     // [N][NH*64]
    const int SP = (NH == 1) ? 1 : 8;
    __shared__ unsigned wpk[4][NH][64];
    __shared__ int jbuf[4][64];
    __shared__ float red[4][584];
    int node = (blockIdx.x * 256 + threadIdx.x) >> 6;
    int lane = threadIdx.x & 63;
    int wv = threadIdx.x >> 6;
    if (node >= N_NODES) return;
    int deg = cnt[node];
    const int RS = NH * 64;
    // dst-scores for this node (wave-uniform broadcast loads)
    float da[NH];
    if constexpr (NH == 1) {
        da[0] = a_dst[node];
    } else {
        float4 d0 = *(const float4*)(a_dst + (size_t)node * SP);
        da[0] = d0.x; da[1] = d0.y; da[2] = d0.z; da[3] = d0.w;
        da[4] = a_dst[(size_t)node * SP + 4];
    }
    if (deg <= BCAP) {
        int es = lane >> 3, cg = lane & 7;
        int joff = 0;
        float e[NH];
#pragma unroll
        for (int h = 0; h < NH; ++h) e[h] = 0.f;
        if (lane < deg) {
            int j = esrc2[node * BCAP + lane];
            joff = j * RS;
            if constexpr (NH == 1) {
                e[0] = __expf(leaky(a_src[j] + da[0]));
            } else {
                float4 s0 = *(const float4*)(a_src + (size_t)j * SP);
                float s4 = a_src[(size_t)j * SP + 4];
                e[0] = __expf(leaky(s0.x + da[0]));
                e[1] = __expf(leaky(s0.y + da[1]));
                e[2] = __expf(leaky(s0.z + da[2]));
                e[3] = __expf(leaky(s0.w + da[3]));
                e[4] = __expf(leaky(s4 + da[4]));
            }
        }
        float s[NH];
#pragma unroll
        for (int h = 0; h < NH; ++h) s[h] = e[h];
#pragma unroll
        for (int off = 1; off < 64; off <<= 1) {
#pragma unroll
            for (int h = 0; h < NH; ++h) s[h] += __shfl_xor(s[h], off, 64);
        }
#pragma unroll
        for (int h = 0; h < NH; ++h) {
            float r = 1.f / (s[h] + 1e-16f);
            __half2 wn = __float2half2_rn(e[h] * r);
            wpk[wv][h][lane] = *(unsigned*)&wn;
        }
        jbuf[wv][lane] = joff;
        const __half* base = hf + cg * 8;
        __half* zrow = zout + (size_t)node * RS;
        if (deg <= 16) {
            gather_pipe<NH, 2, RELU>(base, wpk[wv], jbuf[wv], red[wv], bias, zrow, es, cg, lane);
        } else if (deg <= 32) {
            gather_pipe<NH, 4, RELU>(base, wpk[wv], jbuf[wv], red[wv], bias, zrow, es, cg, lane);
        } else {
            // legacy serial path (deg in (32,64], ~0.04% of nodes)
#pragma unroll
            for (int h = 0; h < NH; ++h) {
                const __half* hbase = hf + h * 64 + cg * 8;
                __half2 acch[4] = {__half2{0, 0}, __half2{0, 0}, __half2{0, 0}, __half2{0, 0}};
                for (int k0 = 0; k0 < deg; k0 += 32) {
                    int kA = k0 + es, kB = kA + 8, kC = kA + 16, kD = kA + 24;
                    unsigned uA = wpk[wv][h][kA];
                    unsigned uB = wpk[wv][h][kB];
                    unsigned uC = wpk[wv][h][kC];
                    unsigned uD = wpk[wv][h][kD];
                    int jA = jbuf[wv][kA];
                    int jB = jbuf[wv][kB];
                    int jC = jbuf[wv][kC];
                    int jD = jbuf[wv][kD];
                    float4 vA = *(const float4*)(hbase + jA);
                    float4 vB = *(const float4*)(hbase + jB);
                    float4 vC = *(const float4*)(hbase + jC);
                    float4 vD = *(const float4*)(hbase + jD);
                    __half2 hwA = *(__half2*)&uA, hwB = *(__half2*)&uB;
                    __half2 hwC = *(__half2*)&uC, hwD = *(__half2*)&uD;
                    const __half2* pA = (const __half2*)&vA;
                    const __half2* pB = (const __half2*)&vB;
                    const __half2* pC = (const __half2*)&vC;
                    const __half2* pD = (const __half2*)&vD;
#pragma unroll
                    for (int i = 0; i < 4; ++i) {
                        acch[i] = __hfma2(pA[i], hwA, acch[i]);
                        acch[i] = __hfma2(pB[i], hwB, acch[i]);
                        acch[i] = __hfma2(pC[i], hwC, acch[i]);
                        acch[i] = __hfma2(pD[i], hwD, acch[i]);
                    }
                }
#pragma unroll
                for (int i = 0; i < 4; ++i) {
                    float2 f = __half22float2(acch[i]);
                    red[wv][(cg * 8 + 2 * i) * 9 + es] = f.x;
                    red[wv][(cg * 8 + 2 * i + 1) * 9 + es] = f.y;
                }
                float tot = 0.f;
#pragma unroll
                for (int e2 = 0; e2 < 8; ++e2)
                    tot += red[wv][lane * 9 + e2];
                float o = tot + bias[h * 64 + lane];
                if (RELU) o = fmaxf(o, 0.f);
                zrow[h * 64 + lane] = __float2half(o);
            }
        }
    } else {
        // cold path: deg > BCAP. lane = channel; bucket (64 full) + overflow scan.
        int ovn = min(*ovf_cnt, OVF_CAP);
#pragma unroll
        for (int h = 0; h < NH; ++h) {
            float adsth = da[h];
            float sden = __expf(leaky(a_src[(size_t)esrc2[node * BCAP + lane] * SP + h] + adsth));
#pragma unroll
            for (int off = 1; off < 64; off <<= 1)
                sden += __shfl_xor(sden, off, 64);
            float s2 = 0.f;
            for (int k = lane; k < ovn; k += 64)
                if (ovf[2 * k] == node)
                    s2 += __expf(leaky(a_src[(size_t)ovf[2 * k + 1] * SP + h] + adsth));
#pragma unroll
            for (int off = 1; off < 64; off <<= 1)
                s2 += __shfl_xor(s2, off, 64);
            float r = 1.f / (sden + s2 + 1e-16f);
            float a = 0.f;
            for (int k = 0; k < BCAP; ++k) {
                int j = esrc2[node * BCAP + k];
                float w = __expf(leaky(a_src[(size_t)j * SP + h] + adsth));
                a += w * __half2float(hf[(size_t)j * RS + h * 64 + lane]);
            }
            for (int k = 0; k < ovn; ++k) {
                if (ovf[2 * k] == node) {
                    int j = ovf[2 * k + 1];
                    float w = __expf(leaky(a_src[(size_t)j * SP + h] + adsth));
                    a += w * __half2float(hf[(size_t)j * RS + h * 64 + lane]);
                }
            }
            float o = a * r + bias[h * 64 + lane];
            if (RELU) o = fmaxf(o, 0.f);
            zout[(size_t)node * RS + h * 64 + lane] = __float2half(o);
        }
    }
}

// ================ layer-2 GEMM (slot-strided, 256-thr blocks) ================
__global__ __launch_bounds__(256) void k_gemm2(const __half* __restrict__ z1,
                                               const __half* __restrict__ Wt2,
                                               __half* __restrict__ h2,
                                               const float* __restrict__ att_src2,
                                               const float* __restrict__ att_dst2,
                                               float* __restrict__ as2,
                                               float* __restrict__ ad2) {
    int lane = threadIdx.x & 63, wv = threadIdx.x >> 6;
    gemm_phase<1, 1, __half>(z1, Wt2, h2, D1, att_src2, att_dst2, as2, ad2,
                             blockIdx.x * 4 + wv, gridDim.x * 4, lane);
}

// ================ decode: 8 lanes per edge, 16B fp16 loads, fdot2 ================
__global__ __launch_bounds__(256) void k_decode(const int* __restrict__ pos,
                                                const int* __restrict__ neg,
                                                const __half* __restrict__ z2,
                                                float* __restrict__ out) {
    int t = blockIdx.x * 256 + threadIdx.x;
    int e = t >> 3;
    int lc = t & 7;
    if (e >= 2 * PE_CNT) return;
    int a, b;
    if (e < PE_CNT) { a = pos[e]; b = pos[PE_CNT + e]; }
    else { int k = e - PE_CNT; a = neg[k]; b = neg[PE_CNT + k]; }
    union U { float4 f; f16x2 h[4]; __half2 hh[4]; } ua, ub;
    ua.f = *(const float4*)(z2 + (size_t)a * OUT_CH + lc * 8);
    ub.f = *(const float4*)(z2 + (size_t)b * OUT_CH + lc * 8);
    float v = 0.f;
#pragma unroll
    for (int i = 0; i < 4; ++i) {
#ifdef HAS_FDOT2
        v = __builtin_amdgcn_fdot2(ua.h[i], ub.h[i], v, false);
#else
        float2 fa = __half22float2(ua.hh[i]);
        float2 fb = __half22float2(ub.hh[i]);
        v += fa.x * fb.x + fa.y * fb.y;
#endif
    }
#pragma unroll
    for (int off = 1; off < 8; off <<= 1)
        v += __shfl_xor(v, off, 64);
    if (lc == 0) out[e] = v;
}

extern "C" void kernel_launch(void* const* d_in, const int* in_sizes, int n_in,
                              void* d_out, int out_size, void* d_ws, size_t ws_size,
                              hipStream_t stream) {
    const float* x        = (const float*)d_in[0];
    const int* edge_index = (const int*)d_in[1];
    const int* pos_ei     = (const int*)d_in[2];
    const int* neg_ei     = (const int*)d_in[3];
    const float* W1       = (const float*)d_in[4];
    const float* att_src1 = (const float*)d_in[5];
    const float* att_dst1 = (const float*)d_in[6];
    const float* b1       = (const float*)d_in[7];
    const float* W2       = (const float*)d_in[8];
    const float* att_src2 = (const float*)d_in[9];
    const float* att_dst2 = (const float*)d_in[10];
    const float* b2       = (const float*)d_in[11];
    float* out            = (float*)d_out;

    char* ws = (char*)d_ws;
    size_t off = 0;
    auto alloc = [&](size_t bytes) -> void* {
        void* p = ws + off;
        off = (off + bytes + 255) & ~(size_t)255;
        return p;
    };
    int* cnt     = (int*)alloc(sizeof(int) * N_NODES);
    int* ovfc    = (int*)alloc(sizeof(int) * 8);
    int* esrc2   = (int*)alloc(sizeof(int) * (size_t)N_NODES * BCAP);
    int* ovf     = (int*)alloc(sizeof(int) * (size_t)2 * OVF_CAP); // 512KB capped
    __half* h1   = (__half*)alloc(sizeof(__half) * (size_t)N_NODES * D1);
    __half* z1   = (__half*)alloc(sizeof(__half) * (size_t)N_NODES * D1);
    __half* h2   = (__half*)alloc(sizeof(__half) * (size_t)N_NODES * OUT_CH);
    __half* z2   = (__half*)alloc(sizeof(__half) * (size_t)N_NODES * OUT_CH);
    __half* Wt1  = (__half*)alloc(sizeof(__half) * (size_t)D1 * IN_CH);
    __half* Wt2  = (__half*)alloc(sizeof(__half) * (size_t)OUT_CH * D1);
    float* as1   = (float*)alloc(sizeof(float) * (size_t)N_NODES * 8); // [N][8] node-major, 5 used
    float* ad1   = (float*)alloc(sizeof(float) * (size_t)N_NODES * 8); // [N][8]
    float* as2   = (float*)alloc(sizeof(float) * (size_t)N_NODES);
    float* ad2   = (float*)alloc(sizeof(float) * (size_t)N_NODES);
    // partA/offA (7.2MB each) ALIAS z1's 19.2MB: both are dead after k_rank,
    // and z1 is first written in K2 which stream-orders after k_rank. 256-aligned
    // (7,200,000 % 256 == 0). Keeps total ws ~56.7MB (R24's separate allocations
    // hit 74.6MB and crashed the ~64MB workspace).
    unsigned* partA = (unsigned*)z1;
    unsigned* offA  = (unsigned*)((char*)z1 + (size_t)BB * NW * sizeof(unsigned));

    // K0: init (self-loops, ovfc, weight prep) || pass A (LDS histogram -> partA)
    k_init<<<INIT_BLOCKS + BB, 512, 0, stream>>>(ovfc, esrc2, W1, Wt1, W2, Wt2,
                                                 edge_index, partA);
    // K1: layer-1 MFMA GEMM + scores || prefix (partA -> offA, cnt)
    k_build_gemm1<<<GEMM1_BLOCKS + PFX_BLOCKS, 256, 0, stream>>>(
        partA, offA, cnt, x, Wt1, h1, att_src1, att_dst1, as1, ad1);
    // K1.5: pass B — rank assignment + esrc2 scatter
    k_rank<<<BB, 512, 0, stream>>>(edge_index, offA, esrc2, ovfc, ovf);
    // K2: layer-1 softmax-aggregate (+relu) — one wave per node, 5 heads merged
    k_attn_agg<HEADS1, true><<<(N_NODES + 3) / 4, 256, 0, stream>>>(
        cnt, esrc2, ovfc, ovf, h1, as1, ad1, b1, z1);
    // K3: layer-2 GEMM + scores
    k_gemm2<<<469, 256, 0, stream>>>(z1, Wt2, h2, att_src2, att_dst2, as2, ad2);
    // K4: layer-2 softmax-aggregate
    k_attn_agg<1, false><<<(N_NODES + 3) / 4, 256, 0, stream>>>(
        cnt, esrc2, ovfc, ovf, h2, as2, ad2, b2, z2);
    // K5: decode
    k_decode<<<(2 * PE_CNT * 8 + 255) / 256, 256, 0, stream>>>(pos_ei, neg_ei, z2, out);

    (void)in_sizes; (void)n_in; (void)out_size; (void)ws_size;
}

// Round 9
// 205.806 us; speedup vs baseline: 2.2665x; 1.0006x over previous
//
#include <hip/hip_runtime.h>
#include <hip/hip_fp16.h>
#include <cstdint>
#include <cstddef>
#include <type_traits>

#define N_NODES 30000
#define N_EDGES 480000
#define N_EDGES_SL (N_EDGES + N_NODES) // 510000
#define IN_CH 128
#define HEADS1 5
#define C1 64
#define D1 (HEADS1 * C1) // 320
#define OUT_CH 64
#define PE_CNT 100000
#define NEG_SLOPE 0.2f
#define BCAP 64   // bucket: slot 0 = self-loop, slots 1..deg = edges (exact global ranks)
#define GEMM1_BLOCKS 469
#define INIT_BLOCKS 120     // 512-thr init blocks
#define BB 120              // builder blocks (pass A / pass B), 512 thr each
#define EPB (N_EDGES / BB)  // 4000 edges per builder block (exact)
#define NW (N_NODES / 2)    // 15000 packed u32 words (2 x u16 bins per word)
#define PFX_BLOCKS 59       // prefix blocks: 59*256 = 15104 >= NW
#define OVF_CAP 65536       // overflow list capacity (writes clamped; p(use)~1e-18)
// R28: K2 concurrency experiment, clean version. R27's 2-deep pipeline REGRESSED
// K2 (48.9->53.4, VALUBusy 41->32, VGPR stuck at 40): the manual vA=nA rotation
// forced register-move serialization — implementation artifact, not physics.
// R28: issue ALL NH*NS gather loads UP FRONT (deg<=32 = 99.96% of nodes: 5 heads
// x 4 slots = 20 independent float4 = 80 VGPR in flight), one waitcnt, then
// consume+epilogue per head. Sharp signatures: VGPR must rise to >=100 (else the
// compiler defeated it again); latency-bound -> K2 ~32-38us, VALUBusy >=50%;
// flat ~49 with VGPR>=100 -> ~3TB/s is this gather's ceiling (FETCH 148MB is AT
// the 8-XCD x h1 compulsory floor) -> K2 done, pivot to the invisible tail.
// Build scheme (R25-proven, untouched): two-pass counting sort, each edge
// visited exactly twice, zero global returning atomics (R19-R21: ~8/ns cap).

typedef _Float16 f16x8 __attribute__((ext_vector_type(8)));
typedef _Float16 f16x2 __attribute__((ext_vector_type(2)));
typedef float fx4 __attribute__((ext_vector_type(4)));

#if defined(__has_builtin)
#if __has_builtin(__builtin_amdgcn_fdot2)
#define HAS_FDOT2 1
#endif
#endif

static __device__ __forceinline__ float leaky(float x) {
    return fmaxf(x, NEG_SLOPE * x); // valid for 0<slope<1
}

// ---------------- barrier-free MFMA fp16 GEMM phase + fused attention scores ----------------
// Wave-slot per 16-row tile (30000 = 16*1875). No LDS, no barriers.
// mfma_f32_16x16x32_f16 layouts (HW-verified): A: lane holds A[m=lane&15][k=quad*8+j];
// B: lane holds B[k=quad*8+j][n=lane&15] (contiguous in Wt[n][k]); D: D[row=quad*4+reg][col=lane&15].
// Scores written NODE-MAJOR with stride SP: as_out[row*SP + h].
template<int NH, int SP, typename AT>
static __device__ __forceinline__ void gemm_phase(const AT* __restrict__ A,
                                                  const __half* __restrict__ Wt,
                                                  __half* __restrict__ C, int K,
                                                  const float* __restrict__ att_src,
                                                  const float* __restrict__ att_dst,
                                                  float* __restrict__ as_out,
                                                  float* __restrict__ ad_out,
                                                  int slot, int nsl, int lane) {
    const int N = NH * 64;
    int q = lane >> 4, l16 = lane & 15;
    for (int tile = slot; tile < N_NODES / 16; tile += nsl) {
        int rowBase = tile * 16;
        int arow = rowBase + l16;
        fx4 zero4 = {0.f, 0.f, 0.f, 0.f};
        fx4 acc[NH][4];
#pragma unroll
        for (int h = 0; h < NH; ++h)
#pragma unroll
            for (int c = 0; c < 4; ++c) acc[h][c] = zero4;
        for (int kk = 0; kk < K; kk += 32) {
            f16x8 af;
            if constexpr (std::is_same<AT, float>::value) {
                const float4* s = (const float4*)(A + (size_t)arow * K + kk + q * 8);
                float4 v0 = s[0], v1 = s[1];
                af[0] = (_Float16)v0.x; af[1] = (_Float16)v0.y;
                af[2] = (_Float16)v0.z; af[3] = (_Float16)v0.w;
                af[4] = (_Float16)v1.x; af[5] = (_Float16)v1.y;
                af[6] = (_Float16)v1.z; af[7] = (_Float16)v1.w;
            } else {
                af = *(const f16x8*)((const __half*)A + (size_t)arow * K + kk + q * 8);
            }
#pragma unroll
            for (int h = 0; h < NH; ++h) {
#pragma unroll
                for (int c = 0; c < 4; ++c) {
                    int col = h * 64 + c * 16 + l16;
                    f16x8 bf = *(const f16x8*)(Wt + (size_t)col * K + kk + q * 8);
                    acc[h][c] = __builtin_amdgcn_mfma_f32_16x16x32_f16(af, bf, acc[h][c], 0, 0, 0);
                }
            }
        }
#pragma unroll
        for (int h = 0; h < NH; ++h) {
            float ps[4] = {0.f, 0.f, 0.f, 0.f};
            float pd[4] = {0.f, 0.f, 0.f, 0.f};
#pragma unroll
            for (int c = 0; c < 4; ++c) {
                int gcol = h * 64 + c * 16 + l16;
                float av = att_src[gcol];
                float dv = att_dst[gcol];
#pragma unroll
                for (int reg = 0; reg < 4; ++reg) {
                    int grow = rowBase + q * 4 + reg;
                    float val = acc[h][c][reg];
                    C[(size_t)grow * N + gcol] = __float2half(val);
                    ps[reg] += val * av;
                    pd[reg] += val * dv;
                }
            }
#pragma unroll
            for (int off = 1; off < 16; off <<= 1) {
#pragma unroll
                for (int reg = 0; reg < 4; ++reg) {
                    ps[reg] += __shfl_xor(ps[reg], off, 64);
                    pd[reg] += __shfl_xor(pd[reg], off, 64);
                }
            }
            if (l16 == 0) {
#pragma unroll
                for (int reg = 0; reg < 4; ++reg) {
                    int grow = rowBase + q * 4 + reg;
                    as_out[(size_t)grow * SP + h] = ps[reg];
                    ad_out[(size_t)grow * SP + h] = pd[reg];
                }
            }
        }
    }
}

// ================ K0 (512-thr): init (self-loops, ovfc, weight transpose) || pass A histogram ================
__global__ __launch_bounds__(512) void k_init(int* __restrict__ ovfc,
                                              int* __restrict__ esrc2,
                                              const float* __restrict__ W1,
                                              __half* __restrict__ Wt1,
                                              const float* __restrict__ W2,
                                              __half* __restrict__ Wt2,
                                              const int* __restrict__ edge,
                                              unsigned* __restrict__ partA) {
    __shared__ unsigned bins[NW]; // 60000 B
    if (blockIdx.x < INIT_BLOCKS) {
        int t = blockIdx.x * 512 + threadIdx.x;
        int nthr = INIT_BLOCKS * 512; // 61440
        for (int i = t; i < N_NODES; i += nthr) esrc2[i * BCAP] = i; // self-loop = slot 0
        if (t == 0) *ovfc = 0;
        const int T1 = IN_CH * D1, T2 = D1 * OUT_CH; // 40960 + 20480 = 61440
        for (int idx = t; idx < T1 + T2; idx += nthr) {
            if (idx < T1) {
                int k = idx / D1, n = idx - k * D1;
                Wt1[(size_t)n * IN_CH + k] = __float2half(W1[idx]);
            } else {
                int i2 = idx - T1;
                int k = i2 / OUT_CH, n = i2 - k * OUT_CH;
                Wt2[(size_t)n * D1 + k] = __float2half(W2[i2]);
            }
        }
    } else {
        int b = blockIdx.x - INIT_BLOCKS; // 0..119
        for (int i = threadIdx.x; i < NW; i += 512) bins[i] = 0;
        __syncthreads();
        int e0 = b * EPB;
        for (int e = e0 + ((int)threadIdx.x << 2); e < e0 + EPB; e += 2048) {
            int4 dd = *(const int4*)(edge + N_EDGES + e);
            atomicAdd(&bins[dd.x >> 1], (dd.x & 1) ? 65536u : 1u);
            atomicAdd(&bins[dd.y >> 1], (dd.y & 1) ? 65536u : 1u);
            atomicAdd(&bins[dd.z >> 1], (dd.z & 1) ? 65536u : 1u);
            atomicAdd(&bins[dd.w >> 1], (dd.w & 1) ? 65536u : 1u);
        }
        __syncthreads();
        for (int i = threadIdx.x; i < NW; i += 512)
            partA[(size_t)b * NW + i] = bins[i];
    }
}

// ================ K1: layer-1 GEMM || prefix over block-partials (10-wide batched) ================
__global__ __launch_bounds__(256) void k_build_gemm1(const unsigned* __restrict__ partA,
                                                     unsigned* __restrict__ offA,
                                                     int* __restrict__ cnt,
                                                     const float* __restrict__ x,
                                                     const __half* __restrict__ Wt1,
                                                     __half* __restrict__ h1,
                                                     const float* __restrict__ att_src1,
                                                     const float* __restrict__ att_dst1,
                                                     float* __restrict__ as1,
                                                     float* __restrict__ ad1) {
    int lane = threadIdx.x & 63, wv = threadIdx.x >> 6;
    if (blockIdx.x < GEMM1_BLOCKS) {
        gemm_phase<HEADS1, 8, float>(x, Wt1, h1, IN_CH, att_src1, att_dst1, as1, ad1,
                                     blockIdx.x * 4 + wv, GEMM1_BLOCKS * 4, lane);
    } else {
        int w = (blockIdx.x - GEMM1_BLOCKS) * 256 + threadIdx.x;
        if (w < NW) {
            unsigned s0 = 1, s1 = 1; // slot 0 = self-loop
            for (int b0 = 0; b0 < BB; b0 += 10) {
                unsigned v[10];
#pragma unroll
                for (int u = 0; u < 10; ++u)
                    v[u] = partA[(size_t)(b0 + u) * NW + w];
#pragma unroll
                for (int u = 0; u < 10; ++u) {
                    offA[(size_t)(b0 + u) * NW + w] = min(s0, 64u) | (min(s1, 64u) << 16);
                    s0 += v[u] & 0xFFFFu;
                    s1 += v[u] >> 16;
                }
            }
            cnt[2 * w] = (int)s0;
            cnt[2 * w + 1] = (int)s1;
        }
    }
}

// ================ K1.5 (512-thr): pass B — rank + scatter (all lanes active) ================
__global__ __launch_bounds__(512) void k_rank(const int* __restrict__ edge,
                                              const unsigned* __restrict__ offA,
                                              int* __restrict__ esrc2,
                                              int* __restrict__ ovf_cnt,
                                              int* __restrict__ ovf) {
    __shared__ unsigned bins[NW];
    int b = blockIdx.x;
    for (int i = threadIdx.x; i < NW; i += 512) bins[i] = 0;
    __syncthreads();
    int e0 = b * EPB;
    for (int e = e0 + ((int)threadIdx.x << 2); e < e0 + EPB; e += 2048) {
        int4 dd = *(const int4*)(edge + N_EDGES + e);
        int4 ss = *(const int4*)(edge + e);
        int dv[4] = {dd.x, dd.y, dd.z, dd.w};
        int sv[4] = {ss.x, ss.y, ss.z, ss.w};
#pragma unroll
        for (int u = 0; u < 4; ++u) {
            int d = dv[u];
            unsigned ret = atomicAdd(&bins[d >> 1], (d & 1) ? 65536u : 1u);
            unsigned lr = (d & 1) ? (ret >> 16) : (ret & 0xFFFFu);
            unsigned off = offA[(size_t)b * NW + (d >> 1)];
            off = (d & 1) ? (off >> 16) : (off & 0xFFFFu);
            unsigned slot = off + lr;
            if (slot < BCAP) {
                esrc2[(d << 6) + slot] = sv[u];
            } else { // true global rank >= 64 (off clamped at 64 keeps this exact)
                int oi = atomicAdd(ovf_cnt, 1);
                if (oi < OVF_CAP) { ovf[2 * oi] = d; ovf[2 * oi + 1] = sv[u]; }
            }
        }
    }
}

// ---------------- R28: all-heads-upfront gather — NH*NS independent loads in flight ----------------
// NS = slots (2 for deg<=16, 4 for deg<=32). All loads issued before any consume;
// single implicit waitcnt; per-head consume + LDS pad-9 epilogue after. Arrays are
// fully-unrolled compile-time indexed (no scratch). Invalid slots carry weight 0.
template<int NH, int NS, bool RELU>
static __device__ __forceinline__ void gather_all(const __half* __restrict__ base, // hf + cg*8
                                                  const unsigned (&wpkw)[NH][64],
                                                  const int (&jbufw)[64],
                                                  float (&redw)[584],
                                                  const float* __restrict__ bias,
                                                  __half* __restrict__ zrow, // zout + node*RS
                                                  int es, int cg, int lane) {
    int kA = es, kB = es + 8, kC = es + 16, kD = es + 24;
    int jA = jbufw[kA], jB = jbufw[kB];
    int jC = (NS == 4) ? jbufw[kC] : 0;
    int jD = (NS == 4) ? jbufw[kD] : 0;
    float4 v[NH][4];
#pragma unroll
    for (int h = 0; h < NH; ++h) {
        const __half* hb = base + h * 64;
        v[h][0] = *(const float4*)(hb + jA);
        v[h][1] = *(const float4*)(hb + jB);
        if (NS == 4) {
            v[h][2] = *(const float4*)(hb + jC);
            v[h][3] = *(const float4*)(hb + jD);
        }
    }
#pragma unroll
    for (int h = 0; h < NH; ++h) {
        unsigned uA = wpkw[h][kA], uB = wpkw[h][kB];
        __half2 hwA = *(__half2*)&uA, hwB = *(__half2*)&uB;
        const __half2* pA = (const __half2*)&v[h][0];
        const __half2* pB = (const __half2*)&v[h][1];
        __half2 a2[4] = {__half2{0, 0}, __half2{0, 0}, __half2{0, 0}, __half2{0, 0}};
#pragma unroll
        for (int i = 0; i < 4; ++i) {
            a2[i] = __hfma2(pA[i], hwA, a2[i]);
            a2[i] = __hfma2(pB[i], hwB, a2[i]);
        }
        if (NS == 4) {
            unsigned uC = wpkw[h][kC], uD = wpkw[h][kD];
            __half2 hwC = *(__half2*)&uC, hwD = *(__half2*)&uD;
            const __half2* pC = (const __half2*)&v[h][2];
            const __half2* pD = (const __half2*)&v[h][3];
#pragma unroll
            for (int i = 0; i < 4; ++i) {
                a2[i] = __hfma2(pC[i], hwC, a2[i]);
                a2[i] = __hfma2(pD[i], hwD, a2[i]);
            }
        }
        // epilogue for head h: fp32 cross-es reduce via LDS pad-9 transpose
#pragma unroll
        for (int i = 0; i < 4; ++i) {
            float2 f = __half22float2(a2[i]);
            redw[(cg * 8 + 2 * i) * 9 + es] = f.x;
            redw[(cg * 8 + 2 * i + 1) * 9 + es] = f.y;
        }
        float tot = 0.f;
#pragma unroll
        for (int e2 = 0; e2 < 8; ++e2)
            tot += redw[lane * 9 + e2];
        float o = tot + bias[h * 64 + lane];
        if (RELU) o = fmaxf(o, 0.f);
        zrow[h * 64 + lane] = __float2half(o);
    }
}

// ================ head-merged softmax + aggregate — ONE WAVE PER NODE ================
// Prologue (R21-proven): one esrc2 gather, all heads' scores via one float4 + scalar
// (node-major [j][SP]), NH pipelined shuffle-reduce trees, weights packed in LDS.
// Gather (R28): deg-uniform 3-way -> all-upfront 2-slot (deg<=16) / 4-slot (deg<=32)
// / legacy serial loop (deg in (32,64], ~0.04% of nodes).
template<int NH, bool RELU>
__global__ __launch_bounds__(256) void k_attn_agg(const int* __restrict__ cnt,
                                                  const int* __restrict__ esrc2,
                                                  const int* __restrict__ ovf_cnt,
                                                  const int* __restrict__ ovf,
                                                  const __half* __restrict__ hf,   // [N][NH*64]
                                                  const float* __restrict__ a_src, // [N][SP]
                                                  const float* __restrict__ a_dst, // [N][SP]
                                                  const float* __restrict__ bias,  // [NH*64]
                                                  __half* __restrict__ zout) {     // [N][NH*64]
    const int SP = (NH == 1) ? 1 : 8;
    __shared__ unsigned wpk[4][NH][64];
    __shared__ int jbuf[4][64];
    __shared__ float red[4][584];
    int node = (blockIdx.x * 256 + threadIdx.x) >> 6;
    int lane = threadIdx.x & 63;
    int wv = threadIdx.x >> 6;
    if (node >= N_NODES) return;
    int deg = cnt[node];
    const int RS = NH * 64;
    // dst-scores for this node (wave-uniform broadcast loads)
    float da[NH];
    if constexpr (NH == 1) {
        da[0] = a_dst[node];
    } else {
        float4 d0 = *(const float4*)(a_dst + (size_t)node * SP);
        da[0] = d0.x; da[1] = d0.y; da[2] = d0.z; da[3] = d0.w;
        da[4] = a_dst[(size_t)node * SP + 4];
    }
    if (deg <= BCAP) {
        int es = lane >> 3, cg = lane & 7;
        int joff = 0;
        float e[NH];
#pragma unroll
        for (int h = 0; h < NH; ++h) e[h] = 0.f;
        if (lane < deg) {
            int j = esrc2[node * BCAP + lane];
            joff = j * RS;
            if constexpr (NH == 1) {
                e[0] = __expf(leaky(a_src[j] + da[0]));
            } else {
                float4 s0 = *(const float4*)(a_src + (size_t)j * SP);
                float s4 = a_src[(size_t)j * SP + 4];
                e[0] = __expf(leaky(s0.x + da[0]));
                e[1] = __expf(leaky(s0.y + da[1]));
                e[2] = __expf(leaky(s0.z + da[2]));
                e[3] = __expf(leaky(s0.w + da[3]));
                e[4] = __expf(leaky(s4 + da[4]));
            }
        }
        float s[NH];
#pragma unroll
        for (int h = 0; h < NH; ++h) s[h] = e[h];
#pragma unroll
        for (int off = 1; off < 64; off <<= 1) {
#pragma unroll
            for (int h = 0; h < NH; ++h) s[h] += __shfl_xor(s[h], off, 64);
        }
#pragma unroll
        for (int h = 0; h < NH; ++h) {
            float r = 1.f / (s[h] + 1e-16f);
            __half2 wn = __float2half2_rn(e[h] * r);
            wpk[wv][h][lane] = *(unsigned*)&wn;
        }
        jbuf[wv][lane] = joff;
        const __half* base = hf + cg * 8;
        __half* zrow = zout + (size_t)node * RS;
        if (deg <= 16) {
            gather_all<NH, 2, RELU>(base, wpk[wv], jbuf[wv], red[wv], bias, zrow, es, cg, lane);
        } else if (deg <= 32) {
            gather_all<NH, 4, RELU>(base, wpk[wv], jbuf[wv], red[wv], bias, zrow, es, cg, lane);
        } else {
            // legacy serial path (deg in (32,64], ~0.04% of nodes)
#pragma unroll
            for (int h = 0; h < NH; ++h) {
                const __half* hbase = hf + h * 64 + cg * 8;
                __half2 acch[4] = {__half2{0, 0}, __half2{0, 0}, __half2{0, 0}, __half2{0, 0}};
                for (int k0 = 0; k0 < deg; k0 += 32) {
                    int kA = k0 + es, kB = kA + 8, kC = kA + 16, kD = kA + 24;
                    unsigned uA = wpk[wv][h][kA];
                    unsigned uB = wpk[wv][h][kB];
                    unsigned uC = wpk[wv][h][kC];
                    unsigned uD = wpk[wv][h][kD];
                    int jA = jbuf[wv][kA];
                    int jB = jbuf[wv][kB];
                    int jC = jbuf[wv][kC];
                    int jD = jbuf[wv][kD];
                    float4 vA = *(const float4*)(hbase + jA);
                    float4 vB = *(const float4*)(hbase + jB);
                    float4 vC = *(const float4*)(hbase + jC);
                    float4 vD = *(const float4*)(hbase + jD);
                    __half2 hwA = *(__half2*)&uA, hwB = *(__half2*)&uB;
                    __half2 hwC = *(__half2*)&uC, hwD = *(__half2*)&uD;
                    const __half2* pA = (const __half2*)&vA;
                    const __half2* pB = (const __half2*)&vB;
                    const __half2* pC = (const __half2*)&vC;
                    const __half2* pD = (const __half2*)&vD;
#pragma unroll
                    for (int i = 0; i < 4; ++i) {
                        acch[i] = __hfma2(pA[i], hwA, acch[i]);
                        acch[i] = __hfma2(pB[i], hwB, acch[i]);
                        acch[i] = __hfma2(pC[i], hwC, acch[i]);
                        acch[i] = __hfma2(pD[i], hwD, acch[i]);
                    }
                }
#pragma unroll
                for (int i = 0; i < 4; ++i) {
                    float2 f = __half22float2(acch[i]);
                    red[wv][(cg * 8 + 2 * i) * 9 + es] = f.x;
                    red[wv][(cg * 8 + 2 * i + 1) * 9 + es] = f.y;
                }
                float tot = 0.f;
#pragma unroll
                for (int e2 = 0; e2 < 8; ++e2)
                    tot += red[wv][lane * 9 + e2];
                float o = tot + bias[h * 64 + lane];
                if (RELU) o = fmaxf(o, 0.f);
                zrow[h * 64 + lane] = __float2half(o);
            }
        }
    } else {
        // cold path: deg > BCAP. lane = channel; bucket (64 full) + overflow scan.
        int ovn = min(*ovf_cnt, OVF_CAP);
#pragma unroll
        for (int h = 0; h < NH; ++h) {
            float adsth = da[h];
            float sden = __expf(leaky(a_src[(size_t)esrc2[node * BCAP + lane] * SP + h] + adsth));
#pragma unroll
            for (int off = 1; off < 64; off <<= 1)
                sden += __shfl_xor(sden, off, 64);
            float s2 = 0.f;
            for (int k = lane; k < ovn; k += 64)
                if (ovf[2 * k] == node)
                    s2 += __expf(leaky(a_src[(size_t)ovf[2 * k + 1] * SP + h] + adsth));
#pragma unroll
            for (int off = 1; off < 64; off <<= 1)
                s2 += __shfl_xor(s2, off, 64);
            float r = 1.f / (sden + s2 + 1e-16f);
            float a = 0.f;
            for (int k = 0; k < BCAP; ++k) {
                int j = esrc2[node * BCAP + k];
                float w = __expf(leaky(a_src[(size_t)j * SP + h] + adsth));
                a += w * __half2float(hf[(size_t)j * RS + h * 64 + lane]);
            }
            for (int k = 0; k < ovn; ++k) {
                if (ovf[2 * k] == node) {
                    int j = ovf[2 * k + 1];
                    float w = __expf(leaky(a_src[(size_t)j * SP + h] + adsth));
                    a += w * __half2float(hf[(size_t)j * RS + h * 64 + lane]);
                }
            }
            float o = a * r + bias[h * 64 + lane];
            if (RELU) o = fmaxf(o, 0.f);
            zout[(size_t)node * RS + h * 64 + lane] = __float2half(o);
        }
    }
}

// ================ layer-2 GEMM (slot-strided, 256-thr blocks) ================
__global__ __launch_bounds__(256) void k_gemm2(const __half* __restrict__ z1,
                                               const __half* __restrict__ Wt2,
                                               __half* __restrict__ h2,
                                               const float* __restrict__ att_src2,
                                               const float* __restrict__ att_dst2,
                                               float* __restrict__ as2,
                                               float* __restrict__ ad2) {
    int lane = threadIdx.x & 63, wv = threadIdx.x >> 6;
    gemm_phase<1, 1, __half>(z1, Wt2, h2, D1, att_src2, att_dst2, as2, ad2,
                             blockIdx.x * 4 + wv, gridDim.x * 4, lane);
}

// ================ decode: 8 lanes per edge, 16B fp16 loads, fdot2 ================
__global__ __launch_bounds__(256) void k_decode(const int* __restrict__ pos,
                                                const int* __restrict__ neg,
                                                const __half* __restrict__ z2,
                                                float* __restrict__ out) {
    int t = blockIdx.x * 256 + threadIdx.x;
    int e = t >> 3;
    int lc = t & 7;
    if (e >= 2 * PE_CNT) return;
    int a, b;
    if (e < PE_CNT) { a = pos[e]; b = pos[PE_CNT + e]; }
    else { int k = e - PE_CNT; a = neg[k]; b = neg[PE_CNT + k]; }
    union U { float4 f; f16x2 h[4]; __half2 hh[4]; } ua, ub;
    ua.f = *(const float4*)(z2 + (size_t)a * OUT_CH + lc * 8);
    ub.f = *(const float4*)(z2 + (size_t)b * OUT_CH + lc * 8);
    float v = 0.f;
#pragma unroll
    for (int i = 0; i < 4; ++i) {
#ifdef HAS_FDOT2
        v = __builtin_amdgcn_fdot2(ua.h[i], ub.h[i], v, false);
#else
        float2 fa = __half22float2(ua.hh[i]);
        float2 fb = __half22float2(ub.hh[i]);
        v += fa.x * fb.x + fa.y * fb.y;
#endif
    }
#pragma unroll
    for (int off = 1; off < 8; off <<= 1)
        v += __shfl_xor(v, off, 64);
    if (lc == 0) out[e] = v;
}

extern "C" void kernel_launch(void* const* d_in, const int* in_sizes, int n_in,
                              void* d_out, int out_size, void* d_ws, size_t ws_size,
                              hipStream_t stream) {
    const float* x        = (const float*)d_in[0];
    const int* edge_index = (const int*)d_in[1];
    const int* pos_ei     = (const int*)d_in[2];
    const int* neg_ei     = (const int*)d_in[3];
    const float* W1       = (const float*)d_in[4];
    const float* att_src1 = (const float*)d_in[5];
    const float* att_dst1 = (const float*)d_in[6];
    const float* b1       = (const float*)d_in[7];
    const float* W2       = (const float*)d_in[8];
    const float* att_src2 = (const float*)d_in[9];
    const float* att_dst2 = (const float*)d_in[10];
    const float* b2       = (const float*)d_in[11];
    float* out            = (float*)d_out;

    char* ws = (char*)d_ws;
    size_t off = 0;
    auto alloc = [&](size_t bytes) -> void* {
        void* p = ws + off;
        off = (off + bytes + 255) & ~(size_t)255;
        return p;
    };
    int* cnt     = (int*)alloc(sizeof(int) * N_NODES);
    int* ovfc    = (int*)alloc(sizeof(int) * 8);
    int* esrc2   = (int*)alloc(sizeof(int) * (size_t)N_NODES * BCAP);
    int* ovf     = (int*)alloc(sizeof(int) * (size_t)2 * OVF_CAP); // 512KB capped
    __half* h1   = (__half*)alloc(sizeof(__half) * (size_t)N_NODES * D1);
    __half* z1   = (__half*)alloc(sizeof(__half) * (size_t)N_NODES * D1);
    __half* h2   = (__half*)alloc(sizeof(__half) * (size_t)N_NODES * OUT_CH);
    __half* z2   = (__half*)alloc(sizeof(__half) * (size_t)N_NODES * OUT_CH);
    __half* Wt1  = (__half*)alloc(sizeof(__half) * (size_t)D1 * IN_CH);
    __half* Wt2  = (__half*)alloc(sizeof(__half) * (size_t)OUT_CH * D1);
    float* as1   = (float*)alloc(sizeof(float) * (size_t)N_NODES * 8); // [N][8] node-major, 5 used
    float* ad1   = (float*)alloc(sizeof(float) * (size_t)N_NODES * 8); // [N][8]
    float* as2   = (float*)alloc(sizeof(float) * (size_t)N_NODES);
    float* ad2   = (float*)alloc(sizeof(float) * (size_t)N_NODES);
    // partA/offA (7.2MB each) ALIAS z1's 19.2MB: both are dead after k_rank,
    // and z1 is first written in K2 which stream-orders after k_rank. 256-aligned
    // (7,200,000 % 256 == 0). Keeps total ws ~56.7MB (R24's separate allocations
    // hit 74.6MB and crashed the ~64MB workspace).
    unsigned* partA = (unsigned*)z1;
    unsigned* offA  = (unsigned*)((char*)z1 + (size_t)BB * NW * sizeof(unsigned));

    // K0: init (self-loops, ovfc, weight prep) || pass A (LDS histogram -> partA)
    k_init<<<INIT_BLOCKS + BB, 512, 0, stream>>>(ovfc, esrc2, W1, Wt1, W2, Wt2,
                                                 edge_index, partA);
    // K1: layer-1 MFMA GEMM + scores || prefix (partA -> offA, cnt)
    k_build_gemm1<<<GEMM1_BLOCKS + PFX_BLOCKS, 256, 0, stream>>>(
        partA, offA, cnt, x, Wt1, h1, att_src1, att_dst1, as1, ad1);
    // K1.5: pass B — rank assignment + esrc2 scatter
    k_rank<<<BB, 512, 0, stream>>>(edge_index, offA, esrc2, ovfc, ovf);
    // K2: layer-1 softmax-aggregate (+relu) — one wave per node, 5 heads merged
    k_attn_agg<HEADS1, true><<<(N_NODES + 3) / 4, 256, 0, stream>>>(
        cnt, esrc2, ovfc, ovf, h1, as1, ad1, b1, z1);
    // K3: layer-2 GEMM + scores
    k_gemm2<<<469, 256, 0, stream>>>(z1, Wt2, h2, att_src2, att_dst2, as2, ad2);
    // K4: layer-2 softmax-aggregate
    k_attn_agg<1, false><<<(N_NODES + 3) / 4, 256, 0, stream>>>(
        cnt, esrc2, ovfc, ovf, h2, as2, ad2, b2, z2);
    // K5: decode
    k_decode<<<(2 * PE_CNT * 8 + 255) / 256, 256, 0, stream>>>(pos_ei, neg_ei, z2, out);

    (void)in_sizes; (void)n_in; (void)out_size; (void)ws_size;
}